// Round 1
// 2357.907 us; speedup vs baseline: 1.0378x; 1.0378x over previous
//
#include <hip/hip_runtime.h>
#include <cstddef>
#include <cstdint>

#define LRELU_SLOPE 0.2f
#define SCAN_BLK 256
#define SCAN_ELEMS 2048   // 8 per thread

typedef float f32x4 __attribute__((ext_vector_type(4)));

// m = x @ W (64x64), p = m·a1, q = m·a2   (one wave per row, W resident in VGPRs)
__global__ __launch_bounds__(256, 4) void gemm_pq_kernel(
    const float* __restrict__ x, const float* __restrict__ W,
    const float* __restrict__ a, float* __restrict__ m,
    float* __restrict__ p, float* __restrict__ q, int n)
{
    const int lane = threadIdx.x & 63;

    // Lane `lane` holds column `lane` of W: 64 floats = 16 float4 in VGPRs.
    // w_g = { W[4g+0][lane], W[4g+1][lane], W[4g+2][lane], W[4g+3][lane] }
#define LOADW(g) f32x4 w##g = { W[(4*g+0)*64 + lane], W[(4*g+1)*64 + lane], \
                                W[(4*g+2)*64 + lane], W[(4*g+3)*64 + lane] };
    LOADW(0)  LOADW(1)  LOADW(2)  LOADW(3)
    LOADW(4)  LOADW(5)  LOADW(6)  LOADW(7)
    LOADW(8)  LOADW(9)  LOADW(10) LOADW(11)
    LOADW(12) LOADW(13) LOADW(14) LOADW(15)
#undef LOADW

    const float a1 = a[lane];
    const float a2 = a[64 + lane];

    const int wid     = (int)((blockIdx.x * blockDim.x + threadIdx.x) >> 6);
    const int wstride = (int)((gridDim.x * blockDim.x) >> 6);

    for (int i = wid; i < n; i += wstride) {
        const int iu = __builtin_amdgcn_readfirstlane(i);   // wave-uniform -> scalar loads
        const float* __restrict__ xr = x + (size_t)iu * 64;

        // Force W to stay materialized in VGPRs across the loop: the allocator
        // may not re-sink the 64 W loads into the FMA chain (the round-0 kernel
        // compiled to 44 VGPRs = W re-fetched per row).
        asm volatile("" : "+v"(w0), "+v"(w1), "+v"(w2), "+v"(w3),
                          "+v"(w4), "+v"(w5), "+v"(w6), "+v"(w7),
                          "+v"(w8), "+v"(w9), "+v"(w10), "+v"(w11),
                          "+v"(w12), "+v"(w13), "+v"(w14), "+v"(w15));

        // 4 independent accumulators; same per-acc association as round 0
        float acc0 = 0.f, acc1 = 0.f, acc2 = 0.f, acc3 = 0.f;
#define STEP(g) { acc0 = fmaf(xr[4*g+0], w##g.x, acc0); \
                  acc1 = fmaf(xr[4*g+1], w##g.y, acc1); \
                  acc2 = fmaf(xr[4*g+2], w##g.z, acc2); \
                  acc3 = fmaf(xr[4*g+3], w##g.w, acc3); }
        STEP(0)  STEP(1)  STEP(2)  STEP(3)
        STEP(4)  STEP(5)  STEP(6)  STEP(7)
        STEP(8)  STEP(9)  STEP(10) STEP(11)
        STEP(12) STEP(13) STEP(14) STEP(15)
#undef STEP
        float acc = (acc0 + acc1) + (acc2 + acc3);
        m[(size_t)iu * 64 + lane] = acc;

        float t1 = acc * a1;
        float t2 = acc * a2;
#pragma unroll
        for (int off = 1; off < 64; off <<= 1) {
            t1 += __shfl_xor(t1, off);
            t2 += __shfl_xor(t2, off);
        }
        if (lane == 0) { p[iu] = t1; q[iu] = t2; }
    }
}

// ---------------- CSR build ----------------
__global__ __launch_bounds__(256) void hist1(const int* __restrict__ seg,
                                             int* __restrict__ counts, int base, int E)
{
    int k = blockIdx.x * blockDim.x + threadIdx.x;
    if (k < E) atomicAdd(&counts[base + seg[k]], 1);
}

__global__ __launch_bounds__(256) void hist2(const int* __restrict__ a, const int* __restrict__ b,
                                             int* __restrict__ counts, int baseA, int baseB, int E)
{
    int k = blockIdx.x * blockDim.x + threadIdx.x;
    if (k < E) {
        atomicAdd(&counts[baseA + a[k]], 1);
        atomicAdd(&counts[baseB + b[k]], 1);
    }
}

__global__ __launch_bounds__(SCAN_BLK) void scan_partial(const int* __restrict__ in,
                                                         int* __restrict__ out,
                                                         int* __restrict__ bsums, int n)
{
    __shared__ int lds[SCAN_BLK];
    int base = blockIdx.x * SCAN_ELEMS + threadIdx.x * 8;
    int v[8]; int s = 0;
#pragma unroll
    for (int k = 0; k < 8; ++k) { int x = (base + k < n) ? in[base + k] : 0; v[k] = s; s += x; }
    lds[threadIdx.x] = s;
    __syncthreads();
    int t = s;
    for (int off = 1; off < SCAN_BLK; off <<= 1) {
        int y = (threadIdx.x >= off) ? lds[threadIdx.x - off] : 0;
        __syncthreads();
        t += y;
        lds[threadIdx.x] = t;
        __syncthreads();
    }
    int excl = t - s;
    if (threadIdx.x == SCAN_BLK - 1) bsums[blockIdx.x] = t;
#pragma unroll
    for (int k = 0; k < 8; ++k) if (base + k < n) out[base + k] = excl + v[k];
}

__global__ __launch_bounds__(1024) void scan_top(int* __restrict__ bsums, int nb)
{
    __shared__ int lds[1024];
    int x = (threadIdx.x < nb) ? bsums[threadIdx.x] : 0;
    lds[threadIdx.x] = x;
    __syncthreads();
    int t = x;
    for (int off = 1; off < 1024; off <<= 1) {
        int y = (threadIdx.x >= off) ? lds[threadIdx.x - off] : 0;
        __syncthreads();
        t += y;
        lds[threadIdx.x] = t;
        __syncthreads();
    }
    if (threadIdx.x < nb) bsums[threadIdx.x] = t - x;
}

__global__ __launch_bounds__(256) void scan_addback(int* __restrict__ out,
                                                    const int* __restrict__ bsums, int n)
{
    int i = blockIdx.x * blockDim.x + threadIdx.x;
    if (i < n) out[i] += bsums[i / SCAN_ELEMS];
}

// reverse-fill buckets using counts as countdown cursors
__global__ __launch_bounds__(256) void place1(const int* __restrict__ seg, const int* __restrict__ other,
                                              const int* __restrict__ rs, int* __restrict__ counts,
                                              int* __restrict__ colsAll, int base, int E)
{
    int k = blockIdx.x * blockDim.x + threadIdx.x;
    if (k >= E) return;
    int s = base + seg[k];
    int off = atomicSub(&counts[s], 1) - 1;
    colsAll[rs[s] + off] = other[k];
}

__global__ __launch_bounds__(256) void place2(const int* __restrict__ a, const int* __restrict__ b,
                                              const int* __restrict__ rs, int* __restrict__ counts,
                                              int* __restrict__ colsAll, int baseA, int baseB, int E)
{
    int k = blockIdx.x * blockDim.x + threadIdx.x;
    if (k >= E) return;
    int av = a[k], bv = b[k];
    int sa = baseA + av;
    int offa = atomicSub(&counts[sa], 1) - 1;
    colsAll[rs[sa] + offa] = bv;
    int sb = baseB + bv;
    int offb = atomicSub(&counts[sb], 1) - 1;
    colsAll[rs[sb] + offb] = av;
}

// ---------------- segment aggregation (16 lanes = quarter-wave per row) ----------------
// out[row] += sum_e exp(lrelu(uni[row]+gat[col_e])) * feat[col_e]  / sum_e exp(...)
__global__ __launch_bounds__(256) void seg_agg(
    const int* __restrict__ rs, const int* __restrict__ cols,
    const float* __restrict__ uni, const float* __restrict__ gat,
    const float* __restrict__ feat, float* __restrict__ out, int n)
{
    const int sub = threadIdx.x & 15;                       // float4 index within row
    int row = (int)((blockIdx.x * blockDim.x + threadIdx.x) >> 4);
    if (row >= n) return;
    int e0 = rs[row], e1 = rs[row + 1];
    if (e0 >= e1) return;             // empty row: leave zeros (avoid 0/0)
    const float pu = uni[row];
    const float4* __restrict__ feat4 = (const float4*)feat;
    float4 acc = make_float4(0.f, 0.f, 0.f, 0.f);
    float ssum = 0.f;
    int e = e0;
    for (; e + 1 < e1; e += 2) {
        int c0 = cols[e], c1 = cols[e + 1];
        float g0 = gat[c0], g1 = gat[c1];
        float4 f0 = feat4[(size_t)c0 * 16 + sub];
        float4 f1 = feat4[(size_t)c1 * 16 + sub];
        float t0 = pu + g0; t0 = (t0 > 0.f) ? t0 : LRELU_SLOPE * t0;
        float t1 = pu + g1; t1 = (t1 > 0.f) ? t1 : LRELU_SLOPE * t1;
        float w0 = __expf(t0);
        float w1 = __expf(t1);
        ssum += w0 + w1;
        acc.x = fmaf(w0, f0.x, acc.x); acc.y = fmaf(w0, f0.y, acc.y);
        acc.z = fmaf(w0, f0.z, acc.z); acc.w = fmaf(w0, f0.w, acc.w);
        acc.x = fmaf(w1, f1.x, acc.x); acc.y = fmaf(w1, f1.y, acc.y);
        acc.z = fmaf(w1, f1.z, acc.z); acc.w = fmaf(w1, f1.w, acc.w);
    }
    if (e < e1) {
        int c0 = cols[e];
        float g0 = gat[c0];
        float4 f0 = feat4[(size_t)c0 * 16 + sub];
        float t0 = pu + g0; t0 = (t0 > 0.f) ? t0 : LRELU_SLOPE * t0;
        float w0 = __expf(t0);
        ssum += w0;
        acc.x = fmaf(w0, f0.x, acc.x); acc.y = fmaf(w0, f0.y, acc.y);
        acc.z = fmaf(w0, f0.z, acc.z); acc.w = fmaf(w0, f0.w, acc.w);
    }
    float inv = __frcp_rn(ssum);
    float4* __restrict__ out4 = (float4*)out;
    float4 o = out4[(size_t)row * 16 + sub];
    o.x = fmaf(acc.x, inv, o.x); o.y = fmaf(acc.y, inv, o.y);
    o.z = fmaf(acc.z, inv, o.z); o.w = fmaf(acc.w, inv, o.w);
    out4[(size_t)row * 16 + sub] = o;
}

extern "C" void kernel_launch(void* const* d_in, const int* in_sizes, int n_in,
                              void* d_out, int out_size, void* d_ws, size_t ws_size,
                              hipStream_t stream)
{
    const float* x0 = (const float*)d_in[0];
    const float* x1 = (const float*)d_in[1];
    const float* x2 = (const float*)d_in[2];
    const float* x3 = (const float*)d_in[3];
    const float* hbsW = (const float*)d_in[4];
    const float* hbsA = (const float*)d_in[5];
    const float* hWs  = (const float*)d_in[6];
    const float* hWt  = (const float*)d_in[7];
    const float* hA   = (const float*)d_in[8];
    const int* a0r = (const int*)d_in[9];  const int* a0c = (const int*)d_in[10];
    const int* a1r = (const int*)d_in[11]; const int* a1c = (const int*)d_in[12];
    const int* a2r = (const int*)d_in[13]; const int* a2c = (const int*)d_in[14];
    const int* c3r = (const int*)d_in[15]; const int* c3c = (const int*)d_in[16];
    const int* i1r = (const int*)d_in[17]; const int* i1c = (const int*)d_in[18];
    const int* i2r = (const int*)d_in[19]; const int* i2c = (const int*)d_in[20];
    const int* i3r = (const int*)d_in[21]; const int* i3c = (const int*)d_in[22];

    const int n0 = in_sizes[0] / 64, n1 = in_sizes[1] / 64;
    const int n2 = in_sizes[2] / 64, n3 = in_sizes[3] / 64;
    const int Ea0 = in_sizes[9],  Ea1 = in_sizes[11], Ea2 = in_sizes[13], Ec3 = in_sizes[15];
    const int Ei1 = in_sizes[17], Ei2 = in_sizes[19], Ei3 = in_sizes[21];

    int nm = n0; if (n1 > nm) nm = n1; if (n2 > nm) nm = n2; if (n3 > nm) nm = n3;

    // CSR bases (concatenated rows): adj0,adj1,adj2,c3, i1t(n0), i1s(n1), i2t(n1), i2s(n2), i3t(n2), i3s(n3)
    int b_adj0 = 0;
    int b_adj1 = b_adj0 + n0;
    int b_adj2 = b_adj1 + n1;
    int b_c3   = b_adj2 + n2;
    int b_i1t  = b_c3   + n3;
    int b_i1s  = b_i1t  + n0;
    int b_i2t  = b_i1s  + n1;
    int b_i2s  = b_i2t  + n1;
    int b_i3t  = b_i2s  + n2;
    int b_i3s  = b_i3t  + n2;
    int NC     = b_i3s  + n3 + 1;   // +1 sentinel
    long long eTot = (long long)Ea0 + Ea1 + Ea2 + Ec3 + 2LL * (Ei1 + Ei2 + Ei3);

    float* w = (float*)d_ws;
    size_t off = 0;
    auto allocf = [&](size_t nel) { float* r = w + off; off += nel; return r; };
    float* featA = allocf((size_t)nm * 64);
    float* featB = allocf((size_t)nm * 64);
    float* xl10  = allocf((size_t)n0 * 64);   // layer-1 activations (contiguous, one memset)
    float* xl11  = allocf((size_t)n1 * 64);
    float* xl12  = allocf((size_t)n2 * 64);
    float* xl13  = allocf((size_t)n3 * 64);
    float* pA = allocf(nm); float* qA = allocf(nm);
    float* pB = allocf(nm); float* qB = allocf(nm);
    int* counts  = (int*)allocf((size_t)NC);
    int* rs      = (int*)allocf((size_t)NC);
    int* bsums   = (int*)allocf(1024);
    int* colsAll = (int*)allocf((size_t)eTot);

    if (off * sizeof(float) > ws_size) {
        hipMemsetAsync(d_out, 0, (size_t)out_size * sizeof(float), stream);
        return;
    }

    float* out  = (float*)d_out;
    float* out0 = out;
    float* out1 = out0 + (size_t)n0 * 64;
    float* out2 = out1 + (size_t)n1 * 64;
    float* out3 = out2 + (size_t)n2 * 64;

    hipMemsetAsync(xl10, 0, (size_t)(n0 + n1 + n2 + n3) * 64 * sizeof(float), stream);
    hipMemsetAsync(counts, 0, (size_t)NC * sizeof(int), stream);
    hipMemsetAsync(d_out, 0, (size_t)out_size * sizeof(float), stream);

    auto blks = [](int n, int per) { return dim3((unsigned)((n + per - 1) / per)); };

    // ---- CSR build ----
    hist1<<<blks(Ea0, 256), 256, 0, stream>>>(a0r, counts, b_adj0, Ea0);
    hist1<<<blks(Ea1, 256), 256, 0, stream>>>(a1r, counts, b_adj1, Ea1);
    hist1<<<blks(Ea2, 256), 256, 0, stream>>>(a2r, counts, b_adj2, Ea2);
    hist1<<<blks(Ec3, 256), 256, 0, stream>>>(c3r, counts, b_c3,  Ec3);
    hist2<<<blks(Ei1, 256), 256, 0, stream>>>(i1r, i1c, counts, b_i1t, b_i1s, Ei1);
    hist2<<<blks(Ei2, 256), 256, 0, stream>>>(i2r, i2c, counts, b_i2t, b_i2s, Ei2);
    hist2<<<blks(Ei3, 256), 256, 0, stream>>>(i3r, i3c, counts, b_i3t, b_i3s, Ei3);

    int nb = (NC + SCAN_ELEMS - 1) / SCAN_ELEMS;
    scan_partial<<<dim3((unsigned)nb), SCAN_BLK, 0, stream>>>(counts, rs, bsums, NC);
    scan_top<<<dim3(1), 1024, 0, stream>>>(bsums, nb);
    scan_addback<<<blks(NC, 256), 256, 0, stream>>>(rs, bsums, NC);

    place1<<<blks(Ea0, 256), 256, 0, stream>>>(a0r, a0c, rs, counts, colsAll, b_adj0, Ea0);
    place1<<<blks(Ea1, 256), 256, 0, stream>>>(a1r, a1c, rs, counts, colsAll, b_adj1, Ea1);
    place1<<<blks(Ea2, 256), 256, 0, stream>>>(a2r, a2c, rs, counts, colsAll, b_adj2, Ea2);
    place1<<<blks(Ec3, 256), 256, 0, stream>>>(c3r, c3c, rs, counts, colsAll, b_c3,  Ec3);
    place2<<<blks(Ei1, 256), 256, 0, stream>>>(i1r, i1c, rs, counts, colsAll, b_i1t, b_i1s, Ei1);
    place2<<<blks(Ei2, 256), 256, 0, stream>>>(i2r, i2c, rs, counts, colsAll, b_i2t, b_i2s, Ei2);
    place2<<<blks(Ei3, 256), 256, 0, stream>>>(i3r, i3c, rs, counts, colsAll, b_i3t, b_i3s, Ei3);

    // Fixed 1024-block grid: exactly 4 blocks/CU resident (launch_bounds 256,4),
    // each wave grid-strides ~12-48 rows so the 64-load W preload amortizes.
    auto gemm = [&](const float* xx, const float* WW, const float* aa,
                    float* mm, float* pp, float* qq, int n) {
        gemm_pq_kernel<<<dim3(1024), 256, 0, stream>>>(xx, WW, aa, mm, pp, qq, n);
    };
    auto agg = [&](int base, const float* uni, const float* gat,
                   const float* feat, float* outp, int n) {
        seg_agg<<<blks(n, 16), 256, 0, stream>>>(rs + base, colsAll, uni, gat, feat, outp, n);
    };

    // ---------------- Layer 1 ----------------
    gemm(x0, hbsW + 0 * 4096, hbsA + 0 * 128, featA, pA, qA, n0);
    agg(b_adj0, pA, qA, featA, xl10, n0);                          // x00

    gemm(x1, hWs + 0 * 4096, hA + 0 * 128, featA, pA, qA, n1);     // sm
    gemm(x0, hWt + 0 * 4096, hA + 0 * 128, featB, pB, qB, n0);     // tm
    agg(b_i1t, qB, pA, featA, xl10, n0);   // x10: e = lrelu(sm_j·a1 + tm_i·a2)
    agg(b_i1s, qA, pB, featB, xl11, n1);   // x01: f = lrelu(tm_i·a1 + sm_j·a2)

    gemm(x2, hWs + 1 * 4096, hA + 1 * 128, featA, pA, qA, n2);
    gemm(x1, hWt + 1 * 4096, hA + 1 * 128, featB, pB, qB, n1);
    agg(b_i2t, qB, pA, featA, xl11, n1);   // x21
    agg(b_i2s, qA, pB, featB, xl12, n2);   // x12

    gemm(x3, hWs + 2 * 4096, hA + 2 * 128, featA, pA, qA, n3);
    gemm(x2, hWt + 2 * 4096, hA + 2 * 128, featB, pB, qB, n2);
    agg(b_i3t, qB, pA, featA, xl12, n2);   // x32
    agg(b_i3s, qA, pB, featB, xl13, n3);   // x23

    // ---------------- Layer 2 ----------------
    gemm(xl10, hbsW + 1 * 4096, hbsA + 1 * 128, featA, pA, qA, n0);
    agg(b_adj0, pA, qA, featA, out0, n0);                          // y00

    gemm(xl11, hbsW + 2 * 4096, hbsA + 2 * 128, featA, pA, qA, n1);
    agg(b_adj1, pA, qA, featA, out1, n1);                          // y11

    gemm(xl12, hbsW + 3 * 4096, hbsA + 3 * 128, featA, pA, qA, n2);
    agg(b_adj2, pA, qA, featA, out2, n2);                          // y22

    gemm(xl13, hbsW + 4 * 4096, hbsA + 4 * 128, featA, pA, qA, n3);
    agg(b_c3, pA, qA, featA, out3, n3);                            // y33

    // y01 = msg_s of hbns(xl11, xl10, inc1) [Ws3, Wt3, a3]
    gemm(xl11, hWs + 3 * 4096, hA + 3 * 128, featA, pA, qA, n1);
    gemm(xl10, hWt + 3 * 4096, hA + 3 * 128, featB, pB, qB, n0);
    agg(b_i1s, qA, pB, featB, out1, n1);

    // y12 = msg_s of hbns(xl12, xl11, inc2) [Ws4, Wt4, a4]
    gemm(xl12, hWs + 4 * 4096, hA + 4 * 128, featA, pA, qA, n2);
    gemm(xl11, hWt + 4 * 4096, hA + 4 * 128, featB, pB, qB, n1);
    agg(b_i2s, qA, pB, featB, out2, n2);

    // y23 = msg_s of hbns(xl13, xl12, inc3) [Ws5, Wt5, a5]
    gemm(xl13, hWs + 5 * 4096, hA + 5 * 128, featA, pA, qA, n3);
    gemm(xl12, hWt + 5 * 4096, hA + 5 * 128, featB, pB, qB, n2);
    agg(b_i3s, qA, pB, featB, out3, n3);
}

// Round 2
// 1727.282 us; speedup vs baseline: 1.4167x; 1.3651x over previous
//
#include <hip/hip_runtime.h>
#include <cstddef>
#include <cstdint>

#define LRELU_SLOPE 0.2f
#define SCAN_BLK 256
#define SCAN_ELEMS 2048   // 8 per thread

#define XS_STRIDE 68      // 64 + 4 pad: keeps float4 alignment, breaks bank alignment

// m = x @ W (64x64), p = m·a1, q = m·a2
// One block per 64-row tile. W and x-tile staged in LDS. Wave w computes rows
// [16w,16w+16) x all 64 cols; each thread a 4x4 register tile. p,q reduced
// wave-locally via 4-step shfl butterfly (one wave owns all 64 cols of a row).
__global__ __launch_bounds__(256, 4) void gemm_pq_kernel(
    const float* __restrict__ x, const float* __restrict__ W,
    const float* __restrict__ a, float* __restrict__ m,
    float* __restrict__ p, float* __restrict__ q, int n)
{
    __shared__ float xs[64 * XS_STRIDE];
    __shared__ float ws[64 * XS_STRIDE];

    const int t = threadIdx.x;
    const int rbase = blockIdx.x * 64;

    // stage W: 4096 floats = 1024 float4, 4 per thread (coalesced)
    {
        const float4* __restrict__ W4 = (const float4*)W;
#pragma unroll
        for (int u = 0; u < 4; ++u) {
            int f = t + 256 * u;          // float4 index
            int k = f >> 4, g = f & 15;
            float4 v = W4[f];
            *(float4*)&ws[k * XS_STRIDE + 4 * g] = v;
        }
    }
    // stage x tile (row-guarded; OOB rows zero-filled)
    {
        const float4* __restrict__ x4 = (const float4*)x;
#pragma unroll
        for (int u = 0; u < 4; ++u) {
            int f = t + 256 * u;
            int r = f >> 4, g = f & 15;
            float4 v = make_float4(0.f, 0.f, 0.f, 0.f);
            if (rbase + r < n) v = x4[(size_t)(rbase + r) * 16 + g];
            *(float4*)&xs[r * XS_STRIDE + 4 * g] = v;
        }
    }
    __syncthreads();

    const int lane = t & 63;
    const int wv   = t >> 6;
    const int s    = lane & 15;          // col group (16 groups cover all 64 cols)
    const int rg   = lane >> 4;          // row group within wave
    const int c0   = 4 * s;
    const int r0   = 16 * wv + 4 * rg;   // tile-local row base

    float acc[4][4] = {{0.f}};

#pragma unroll 2
    for (int k0 = 0; k0 < 64; k0 += 4) {
        float xr[4][4], wr[4][4];
#pragma unroll
        for (int i = 0; i < 4; ++i) {
            float4 v = *(const float4*)&xs[(r0 + i) * XS_STRIDE + k0];
            xr[i][0] = v.x; xr[i][1] = v.y; xr[i][2] = v.z; xr[i][3] = v.w;
        }
#pragma unroll
        for (int kk = 0; kk < 4; ++kk) {
            float4 v = *(const float4*)&ws[(k0 + kk) * XS_STRIDE + c0];
            wr[kk][0] = v.x; wr[kk][1] = v.y; wr[kk][2] = v.z; wr[kk][3] = v.w;
        }
#pragma unroll
        for (int kk = 0; kk < 4; ++kk)
#pragma unroll
            for (int i = 0; i < 4; ++i)
#pragma unroll
                for (int j = 0; j < 4; ++j)
                    acc[i][j] = fmaf(xr[i][kk], wr[kk][j], acc[i][j]);
    }

    // store m (4 rows x float4, 256B-contiguous per 16-lane group)
#pragma unroll
    for (int i = 0; i < 4; ++i) {
        int r = rbase + r0 + i;
        if (r < n)
            *(float4*)&m[(size_t)r * 64 + c0] =
                make_float4(acc[i][0], acc[i][1], acc[i][2], acc[i][3]);
    }

    // p,q: per-thread partial dot over own 4 cols, then butterfly over 16 col-groups
    const float4 a1v = *(const float4*)&a[c0];
    const float4 a2v = *(const float4*)&a[64 + c0];
    float pp[4], qq[4];
#pragma unroll
    for (int i = 0; i < 4; ++i) {
        pp[i] = fmaf(acc[i][3], a1v.w, fmaf(acc[i][2], a1v.z,
                fmaf(acc[i][1], a1v.y, acc[i][0] * a1v.x)));
        qq[i] = fmaf(acc[i][3], a2v.w, fmaf(acc[i][2], a2v.z,
                fmaf(acc[i][1], a2v.y, acc[i][0] * a2v.x)));
    }
#pragma unroll
    for (int off = 1; off < 16; off <<= 1) {
#pragma unroll
        for (int i = 0; i < 4; ++i) {
            pp[i] += __shfl_xor(pp[i], off);
            qq[i] += __shfl_xor(qq[i], off);
        }
    }
    if (s == 0) {
#pragma unroll
        for (int i = 0; i < 4; ++i) {
            int r = rbase + r0 + i;
            if (r < n) { p[r] = pp[i]; q[r] = qq[i]; }
        }
    }
}

// ---------------- CSR build ----------------
__global__ __launch_bounds__(256) void hist1(const int* __restrict__ seg,
                                             int* __restrict__ counts, int base, int E)
{
    int k = blockIdx.x * blockDim.x + threadIdx.x;
    if (k < E) atomicAdd(&counts[base + seg[k]], 1);
}

__global__ __launch_bounds__(256) void hist2(const int* __restrict__ a, const int* __restrict__ b,
                                             int* __restrict__ counts, int baseA, int baseB, int E)
{
    int k = blockIdx.x * blockDim.x + threadIdx.x;
    if (k < E) {
        atomicAdd(&counts[baseA + a[k]], 1);
        atomicAdd(&counts[baseB + b[k]], 1);
    }
}

__global__ __launch_bounds__(SCAN_BLK) void scan_partial(const int* __restrict__ in,
                                                         int* __restrict__ out,
                                                         int* __restrict__ bsums, int n)
{
    __shared__ int lds[SCAN_BLK];
    int base = blockIdx.x * SCAN_ELEMS + threadIdx.x * 8;
    int v[8]; int s = 0;
#pragma unroll
    for (int k = 0; k < 8; ++k) { int x = (base + k < n) ? in[base + k] : 0; v[k] = s; s += x; }
    lds[threadIdx.x] = s;
    __syncthreads();
    int t = s;
    for (int off = 1; off < SCAN_BLK; off <<= 1) {
        int y = (threadIdx.x >= off) ? lds[threadIdx.x - off] : 0;
        __syncthreads();
        t += y;
        lds[threadIdx.x] = t;
        __syncthreads();
    }
    int excl = t - s;
    if (threadIdx.x == SCAN_BLK - 1) bsums[blockIdx.x] = t;
#pragma unroll
    for (int k = 0; k < 8; ++k) if (base + k < n) out[base + k] = excl + v[k];
}

__global__ __launch_bounds__(1024) void scan_top(int* __restrict__ bsums, int nb)
{
    __shared__ int lds[1024];
    int x = (threadIdx.x < nb) ? bsums[threadIdx.x] : 0;
    lds[threadIdx.x] = x;
    __syncthreads();
    int t = x;
    for (int off = 1; off < 1024; off <<= 1) {
        int y = (threadIdx.x >= off) ? lds[threadIdx.x - off] : 0;
        __syncthreads();
        t += y;
        lds[threadIdx.x] = t;
        __syncthreads();
    }
    if (threadIdx.x < nb) bsums[threadIdx.x] = t - x;
}

__global__ __launch_bounds__(256) void scan_addback(int* __restrict__ out,
                                                    const int* __restrict__ bsums, int n)
{
    int i = blockIdx.x * blockDim.x + threadIdx.x;
    if (i < n) out[i] += bsums[i / SCAN_ELEMS];
}

// reverse-fill buckets using counts as countdown cursors
__global__ __launch_bounds__(256) void place1(const int* __restrict__ seg, const int* __restrict__ other,
                                              const int* __restrict__ rs, int* __restrict__ counts,
                                              int* __restrict__ colsAll, int base, int E)
{
    int k = blockIdx.x * blockDim.x + threadIdx.x;
    if (k >= E) return;
    int s = base + seg[k];
    int off = atomicSub(&counts[s], 1) - 1;
    colsAll[rs[s] + off] = other[k];
}

__global__ __launch_bounds__(256) void place2(const int* __restrict__ a, const int* __restrict__ b,
                                              const int* __restrict__ rs, int* __restrict__ counts,
                                              int* __restrict__ colsAll, int baseA, int baseB, int E)
{
    int k = blockIdx.x * blockDim.x + threadIdx.x;
    if (k >= E) return;
    int av = a[k], bv = b[k];
    int sa = baseA + av;
    int offa = atomicSub(&counts[sa], 1) - 1;
    colsAll[rs[sa] + offa] = bv;
    int sb = baseB + bv;
    int offb = atomicSub(&counts[sb], 1) - 1;
    colsAll[rs[sb] + offb] = av;
}

// ---------------- segment aggregation (16 lanes = quarter-wave per row) ----------------
// out[row] += sum_e exp(lrelu(uni[row]+gat[col_e])) * feat[col_e]  / sum_e exp(...)
__global__ __launch_bounds__(256) void seg_agg(
    const int* __restrict__ rs, const int* __restrict__ cols,
    const float* __restrict__ uni, const float* __restrict__ gat,
    const float* __restrict__ feat, float* __restrict__ out, int n)
{
    const int sub = threadIdx.x & 15;                       // float4 index within row
    int row = (int)((blockIdx.x * blockDim.x + threadIdx.x) >> 4);
    if (row >= n) return;
    int e0 = rs[row], e1 = rs[row + 1];
    if (e0 >= e1) return;             // empty row: leave zeros (avoid 0/0)
    const float pu = uni[row];
    const float4* __restrict__ feat4 = (const float4*)feat;
    float4 acc = make_float4(0.f, 0.f, 0.f, 0.f);
    float ssum = 0.f;
    int e = e0;
    for (; e + 1 < e1; e += 2) {
        int c0 = cols[e], c1 = cols[e + 1];
        float g0 = gat[c0], g1 = gat[c1];
        float4 f0 = feat4[(size_t)c0 * 16 + sub];
        float4 f1 = feat4[(size_t)c1 * 16 + sub];
        float t0 = pu + g0; t0 = (t0 > 0.f) ? t0 : LRELU_SLOPE * t0;
        float t1 = pu + g1; t1 = (t1 > 0.f) ? t1 : LRELU_SLOPE * t1;
        float w0 = __expf(t0);
        float w1 = __expf(t1);
        ssum += w0 + w1;
        acc.x = fmaf(w0, f0.x, acc.x); acc.y = fmaf(w0, f0.y, acc.y);
        acc.z = fmaf(w0, f0.z, acc.z); acc.w = fmaf(w0, f0.w, acc.w);
        acc.x = fmaf(w1, f1.x, acc.x); acc.y = fmaf(w1, f1.y, acc.y);
        acc.z = fmaf(w1, f1.z, acc.z); acc.w = fmaf(w1, f1.w, acc.w);
    }
    if (e < e1) {
        int c0 = cols[e];
        float g0 = gat[c0];
        float4 f0 = feat4[(size_t)c0 * 16 + sub];
        float t0 = pu + g0; t0 = (t0 > 0.f) ? t0 : LRELU_SLOPE * t0;
        float w0 = __expf(t0);
        ssum += w0;
        acc.x = fmaf(w0, f0.x, acc.x); acc.y = fmaf(w0, f0.y, acc.y);
        acc.z = fmaf(w0, f0.z, acc.z); acc.w = fmaf(w0, f0.w, acc.w);
    }
    float inv = __frcp_rn(ssum);
    float4* __restrict__ out4 = (float4*)out;
    float4 o = out4[(size_t)row * 16 + sub];
    o.x = fmaf(acc.x, inv, o.x); o.y = fmaf(acc.y, inv, o.y);
    o.z = fmaf(acc.z, inv, o.z); o.w = fmaf(acc.w, inv, o.w);
    out4[(size_t)row * 16 + sub] = o;
}

extern "C" void kernel_launch(void* const* d_in, const int* in_sizes, int n_in,
                              void* d_out, int out_size, void* d_ws, size_t ws_size,
                              hipStream_t stream)
{
    const float* x0 = (const float*)d_in[0];
    const float* x1 = (const float*)d_in[1];
    const float* x2 = (const float*)d_in[2];
    const float* x3 = (const float*)d_in[3];
    const float* hbsW = (const float*)d_in[4];
    const float* hbsA = (const float*)d_in[5];
    const float* hWs  = (const float*)d_in[6];
    const float* hWt  = (const float*)d_in[7];
    const float* hA   = (const float*)d_in[8];
    const int* a0r = (const int*)d_in[9];  const int* a0c = (const int*)d_in[10];
    const int* a1r = (const int*)d_in[11]; const int* a1c = (const int*)d_in[12];
    const int* a2r = (const int*)d_in[13]; const int* a2c = (const int*)d_in[14];
    const int* c3r = (const int*)d_in[15]; const int* c3c = (const int*)d_in[16];
    const int* i1r = (const int*)d_in[17]; const int* i1c = (const int*)d_in[18];
    const int* i2r = (const int*)d_in[19]; const int* i2c = (const int*)d_in[20];
    const int* i3r = (const int*)d_in[21]; const int* i3c = (const int*)d_in[22];

    const int n0 = in_sizes[0] / 64, n1 = in_sizes[1] / 64;
    const int n2 = in_sizes[2] / 64, n3 = in_sizes[3] / 64;
    const int Ea0 = in_sizes[9],  Ea1 = in_sizes[11], Ea2 = in_sizes[13], Ec3 = in_sizes[15];
    const int Ei1 = in_sizes[17], Ei2 = in_sizes[19], Ei3 = in_sizes[21];

    int nm = n0; if (n1 > nm) nm = n1; if (n2 > nm) nm = n2; if (n3 > nm) nm = n3;

    // CSR bases (concatenated rows): adj0,adj1,adj2,c3, i1t(n0), i1s(n1), i2t(n1), i2s(n2), i3t(n2), i3s(n3)
    int b_adj0 = 0;
    int b_adj1 = b_adj0 + n0;
    int b_adj2 = b_adj1 + n1;
    int b_c3   = b_adj2 + n2;
    int b_i1t  = b_c3   + n3;
    int b_i1s  = b_i1t  + n0;
    int b_i2t  = b_i1s  + n1;
    int b_i2s  = b_i2t  + n1;
    int b_i3t  = b_i2s  + n2;
    int b_i3s  = b_i3t  + n2;
    int NC     = b_i3s  + n3 + 1;   // +1 sentinel
    long long eTot = (long long)Ea0 + Ea1 + Ea2 + Ec3 + 2LL * (Ei1 + Ei2 + Ei3);

    float* w = (float*)d_ws;
    size_t off = 0;
    auto allocf = [&](size_t nel) { float* r = w + off; off += nel; return r; };
    float* featA = allocf((size_t)nm * 64);
    float* featB = allocf((size_t)nm * 64);
    float* xl10  = allocf((size_t)n0 * 64);   // layer-1 activations (contiguous, one memset)
    float* xl11  = allocf((size_t)n1 * 64);
    float* xl12  = allocf((size_t)n2 * 64);
    float* xl13  = allocf((size_t)n3 * 64);
    float* pA = allocf(nm); float* qA = allocf(nm);
    float* pB = allocf(nm); float* qB = allocf(nm);
    int* counts  = (int*)allocf((size_t)NC);
    int* rs      = (int*)allocf((size_t)NC);
    int* bsums   = (int*)allocf(1024);
    int* colsAll = (int*)allocf((size_t)eTot);

    if (off * sizeof(float) > ws_size) {
        hipMemsetAsync(d_out, 0, (size_t)out_size * sizeof(float), stream);
        return;
    }

    float* out  = (float*)d_out;
    float* out0 = out;
    float* out1 = out0 + (size_t)n0 * 64;
    float* out2 = out1 + (size_t)n1 * 64;
    float* out3 = out2 + (size_t)n2 * 64;

    hipMemsetAsync(xl10, 0, (size_t)(n0 + n1 + n2 + n3) * 64 * sizeof(float), stream);
    hipMemsetAsync(counts, 0, (size_t)NC * sizeof(int), stream);
    hipMemsetAsync(d_out, 0, (size_t)out_size * sizeof(float), stream);

    auto blks = [](int n, int per) { return dim3((unsigned)((n + per - 1) / per)); };

    // ---- CSR build ----
    hist1<<<blks(Ea0, 256), 256, 0, stream>>>(a0r, counts, b_adj0, Ea0);
    hist1<<<blks(Ea1, 256), 256, 0, stream>>>(a1r, counts, b_adj1, Ea1);
    hist1<<<blks(Ea2, 256), 256, 0, stream>>>(a2r, counts, b_adj2, Ea2);
    hist1<<<blks(Ec3, 256), 256, 0, stream>>>(c3r, counts, b_c3,  Ec3);
    hist2<<<blks(Ei1, 256), 256, 0, stream>>>(i1r, i1c, counts, b_i1t, b_i1s, Ei1);
    hist2<<<blks(Ei2, 256), 256, 0, stream>>>(i2r, i2c, counts, b_i2t, b_i2s, Ei2);
    hist2<<<blks(Ei3, 256), 256, 0, stream>>>(i3r, i3c, counts, b_i3t, b_i3s, Ei3);

    int nb = (NC + SCAN_ELEMS - 1) / SCAN_ELEMS;
    scan_partial<<<dim3((unsigned)nb), SCAN_BLK, 0, stream>>>(counts, rs, bsums, NC);
    scan_top<<<dim3(1), 1024, 0, stream>>>(bsums, nb);
    scan_addback<<<blks(NC, 256), 256, 0, stream>>>(rs, bsums, NC);

    place1<<<blks(Ea0, 256), 256, 0, stream>>>(a0r, a0c, rs, counts, colsAll, b_adj0, Ea0);
    place1<<<blks(Ea1, 256), 256, 0, stream>>>(a1r, a1c, rs, counts, colsAll, b_adj1, Ea1);
    place1<<<blks(Ea2, 256), 256, 0, stream>>>(a2r, a2c, rs, counts, colsAll, b_adj2, Ea2);
    place1<<<blks(Ec3, 256), 256, 0, stream>>>(c3r, c3c, rs, counts, colsAll, b_c3,  Ec3);
    place2<<<blks(Ei1, 256), 256, 0, stream>>>(i1r, i1c, rs, counts, colsAll, b_i1t, b_i1s, Ei1);
    place2<<<blks(Ei2, 256), 256, 0, stream>>>(i2r, i2c, rs, counts, colsAll, b_i2t, b_i2s, Ei2);
    place2<<<blks(Ei3, 256), 256, 0, stream>>>(i3r, i3c, rs, counts, colsAll, b_i3t, b_i3s, Ei3);

    // One block per 64-row tile.
    auto gemm = [&](const float* xx, const float* WW, const float* aa,
                    float* mm, float* pp, float* qq, int n) {
        gemm_pq_kernel<<<blks(n, 64), 256, 0, stream>>>(xx, WW, aa, mm, pp, qq, n);
    };
    auto agg = [&](int base, const float* uni, const float* gat,
                   const float* feat, float* outp, int n) {
        seg_agg<<<blks(n, 16), 256, 0, stream>>>(rs + base, colsAll, uni, gat, feat, outp, n);
    };

    // ---------------- Layer 1 ----------------
    gemm(x0, hbsW + 0 * 4096, hbsA + 0 * 128, featA, pA, qA, n0);
    agg(b_adj0, pA, qA, featA, xl10, n0);                          // x00

    gemm(x1, hWs + 0 * 4096, hA + 0 * 128, featA, pA, qA, n1);     // sm
    gemm(x0, hWt + 0 * 4096, hA + 0 * 128, featB, pB, qB, n0);     // tm
    agg(b_i1t, qB, pA, featA, xl10, n0);   // x10: e = lrelu(sm_j·a1 + tm_i·a2)
    agg(b_i1s, qA, pB, featB, xl11, n1);   // x01: f = lrelu(tm_i·a1 + sm_j·a2)

    gemm(x2, hWs + 1 * 4096, hA + 1 * 128, featA, pA, qA, n2);
    gemm(x1, hWt + 1 * 4096, hA + 1 * 128, featB, pB, qB, n1);
    agg(b_i2t, qB, pA, featA, xl11, n1);   // x21
    agg(b_i2s, qA, pB, featB, xl12, n2);   // x12

    gemm(x3, hWs + 2 * 4096, hA + 2 * 128, featA, pA, qA, n3);
    gemm(x2, hWt + 2 * 4096, hA + 2 * 128, featB, pB, qB, n2);
    agg(b_i3t, qB, pA, featA, xl12, n2);   // x32
    agg(b_i3s, qA, pB, featB, xl13, n3);   // x23

    // ---------------- Layer 2 ----------------
    gemm(xl10, hbsW + 1 * 4096, hbsA + 1 * 128, featA, pA, qA, n0);
    agg(b_adj0, pA, qA, featA, out0, n0);                          // y00

    gemm(xl11, hbsW + 2 * 4096, hbsA + 2 * 128, featA, pA, qA, n1);
    agg(b_adj1, pA, qA, featA, out1, n1);                          // y11

    gemm(xl12, hbsW + 3 * 4096, hbsA + 3 * 128, featA, pA, qA, n2);
    agg(b_adj2, pA, qA, featA, out2, n2);                          // y22

    gemm(xl13, hbsW + 4 * 4096, hbsA + 4 * 128, featA, pA, qA, n3);
    agg(b_c3, pA, qA, featA, out3, n3);                            // y33

    // y01 = msg_s of hbns(xl11, xl10, inc1) [Ws3, Wt3, a3]
    gemm(xl11, hWs + 3 * 4096, hA + 3 * 128, featA, pA, qA, n1);
    gemm(xl10, hWt + 3 * 4096, hA + 3 * 128, featB, pB, qB, n0);
    agg(b_i1s, qA, pB, featB, out1, n1);

    // y12 = msg_s of hbns(xl12, xl11, inc2) [Ws4, Wt4, a4]
    gemm(xl12, hWs + 4 * 4096, hA + 4 * 128, featA, pA, qA, n2);
    gemm(xl11, hWt + 4 * 4096, hA + 4 * 128, featB, pB, qB, n1);
    agg(b_i2s, qA, pB, featB, out2, n2);

    // y23 = msg_s of hbns(xl13, xl12, inc3) [Ws5, Wt5, a5]
    gemm(xl13, hWs + 5 * 4096, hA + 5 * 128, featA, pA, qA, n3);
    gemm(xl12, hWs != hWt ? hWt + 5 * 4096 : hWt + 5 * 4096, hA + 5 * 128, featB, pB, qB, n2);
    agg(b_i3s, qA, pB, featB, out3, n3);
}

// Round 3
// 1660.135 us; speedup vs baseline: 1.4740x; 1.0404x over previous
//
#include <hip/hip_runtime.h>
#include <cstddef>
#include <cstdint>

#define LRELU_SLOPE 0.2f
#define SCAN_BLK 256
#define SCAN_ELEMS 2048   // 8 per thread

#define XS_STRIDE 68      // 64 + 4 pad: keeps float4 alignment, breaks bank alignment

// m = x @ W (64x64), p = m·a1, q = m·a2
// One block per 64-row tile. W and x-tile staged in LDS. Wave w computes rows
// [16w,16w+16) x all 64 cols; each thread a 4x4 register tile.
__global__ __launch_bounds__(256, 4) void gemm_pq_kernel(
    const float* __restrict__ x, const float* __restrict__ W,
    const float* __restrict__ a, float* __restrict__ m,
    float* __restrict__ p, float* __restrict__ q, int n)
{
    __shared__ float xs[64 * XS_STRIDE];
    __shared__ float ws[64 * XS_STRIDE];

    const int t = threadIdx.x;
    const int rbase = blockIdx.x * 64;

    // stage W: 4096 floats = 1024 float4, 4 per thread (coalesced)
    {
        const float4* __restrict__ W4 = (const float4*)W;
#pragma unroll
        for (int u = 0; u < 4; ++u) {
            int f = t + 256 * u;          // float4 index
            int k = f >> 4, g = f & 15;
            float4 v = W4[f];
            *(float4*)&ws[k * XS_STRIDE + 4 * g] = v;
        }
    }
    // stage x tile (row-guarded; OOB rows zero-filled)
    {
        const float4* __restrict__ x4 = (const float4*)x;
#pragma unroll
        for (int u = 0; u < 4; ++u) {
            int f = t + 256 * u;
            int r = f >> 4, g = f & 15;
            float4 v = make_float4(0.f, 0.f, 0.f, 0.f);
            if (rbase + r < n) v = x4[(size_t)(rbase + r) * 16 + g];
            *(float4*)&xs[r * XS_STRIDE + 4 * g] = v;
        }
    }
    __syncthreads();

    const int lane = t & 63;
    const int wv   = t >> 6;
    const int s    = lane & 15;          // col group (16 groups cover all 64 cols)
    const int rg   = lane >> 4;          // row group within wave
    const int c0   = 4 * s;
    const int r0   = 16 * wv + 4 * rg;   // tile-local row base

    float acc[4][4] = {{0.f}};

#pragma unroll 2
    for (int k0 = 0; k0 < 64; k0 += 4) {
        float xr[4][4], wr[4][4];
#pragma unroll
        for (int i = 0; i < 4; ++i) {
            float4 v = *(const float4*)&xs[(r0 + i) * XS_STRIDE + k0];
            xr[i][0] = v.x; xr[i][1] = v.y; xr[i][2] = v.z; xr[i][3] = v.w;
        }
#pragma unroll
        for (int kk = 0; kk < 4; ++kk) {
            float4 v = *(const float4*)&ws[(k0 + kk) * XS_STRIDE + c0];
            wr[kk][0] = v.x; wr[kk][1] = v.y; wr[kk][2] = v.z; wr[kk][3] = v.w;
        }
#pragma unroll
        for (int kk = 0; kk < 4; ++kk)
#pragma unroll
            for (int i = 0; i < 4; ++i)
#pragma unroll
                for (int j = 0; j < 4; ++j)
                    acc[i][j] = fmaf(xr[i][kk], wr[kk][j], acc[i][j]);
    }

    // store m (4 rows x float4, 256B-contiguous per 16-lane group)
#pragma unroll
    for (int i = 0; i < 4; ++i) {
        int r = rbase + r0 + i;
        if (r < n)
            *(float4*)&m[(size_t)r * 64 + c0] =
                make_float4(acc[i][0], acc[i][1], acc[i][2], acc[i][3]);
    }

    // p,q: per-thread partial dot over own 4 cols, then butterfly over 16 col-groups
    const float4 a1v = *(const float4*)&a[c0];
    const float4 a2v = *(const float4*)&a[64 + c0];
    float pp[4], qq[4];
#pragma unroll
    for (int i = 0; i < 4; ++i) {
        pp[i] = fmaf(acc[i][3], a1v.w, fmaf(acc[i][2], a1v.z,
                fmaf(acc[i][1], a1v.y, acc[i][0] * a1v.x)));
        qq[i] = fmaf(acc[i][3], a2v.w, fmaf(acc[i][2], a2v.z,
                fmaf(acc[i][1], a2v.y, acc[i][0] * a2v.x)));
    }
#pragma unroll
    for (int off = 1; off < 16; off <<= 1) {
#pragma unroll
        for (int i = 0; i < 4; ++i) {
            pp[i] += __shfl_xor(pp[i], off);
            qq[i] += __shfl_xor(qq[i], off);
        }
    }
    if (s == 0) {
#pragma unroll
        for (int i = 0; i < 4; ++i) {
            int r = rbase + r0 + i;
            if (r < n) { p[r] = pp[i]; q[r] = qq[i]; }
        }
    }
}

// ---------------- CSR build (x4 edge-unrolled for memory-level parallelism) ----
__global__ __launch_bounds__(256) void hist1(const int* __restrict__ seg,
                                             int* __restrict__ counts, int base, int E)
{
    int k0 = (blockIdx.x * blockDim.x + threadIdx.x) * 4;
    if (k0 + 3 < E) {
        int4 s4 = *(const int4*)&seg[k0];
        atomicAdd(&counts[base + s4.x], 1);
        atomicAdd(&counts[base + s4.y], 1);
        atomicAdd(&counts[base + s4.z], 1);
        atomicAdd(&counts[base + s4.w], 1);
    } else {
        for (int k = k0; k < E; ++k) atomicAdd(&counts[base + seg[k]], 1);
    }
}

__global__ __launch_bounds__(256) void hist2(const int* __restrict__ a, const int* __restrict__ b,
                                             int* __restrict__ counts, int baseA, int baseB, int E)
{
    int k0 = (blockIdx.x * blockDim.x + threadIdx.x) * 4;
    if (k0 + 3 < E) {
        int4 a4 = *(const int4*)&a[k0];
        int4 b4 = *(const int4*)&b[k0];
        atomicAdd(&counts[baseA + a4.x], 1);
        atomicAdd(&counts[baseA + a4.y], 1);
        atomicAdd(&counts[baseA + a4.z], 1);
        atomicAdd(&counts[baseA + a4.w], 1);
        atomicAdd(&counts[baseB + b4.x], 1);
        atomicAdd(&counts[baseB + b4.y], 1);
        atomicAdd(&counts[baseB + b4.z], 1);
        atomicAdd(&counts[baseB + b4.w], 1);
    } else {
        for (int k = k0; k < E; ++k) {
            atomicAdd(&counts[baseA + a[k]], 1);
            atomicAdd(&counts[baseB + b[k]], 1);
        }
    }
}

__global__ __launch_bounds__(SCAN_BLK) void scan_partial(const int* __restrict__ in,
                                                         int* __restrict__ out,
                                                         int* __restrict__ bsums, int n)
{
    __shared__ int lds[SCAN_BLK];
    int base = blockIdx.x * SCAN_ELEMS + threadIdx.x * 8;
    int v[8]; int s = 0;
#pragma unroll
    for (int k = 0; k < 8; ++k) { int x = (base + k < n) ? in[base + k] : 0; v[k] = s; s += x; }
    lds[threadIdx.x] = s;
    __syncthreads();
    int t = s;
    for (int off = 1; off < SCAN_BLK; off <<= 1) {
        int y = (threadIdx.x >= off) ? lds[threadIdx.x - off] : 0;
        __syncthreads();
        t += y;
        lds[threadIdx.x] = t;
        __syncthreads();
    }
    int excl = t - s;
    if (threadIdx.x == SCAN_BLK - 1) bsums[blockIdx.x] = t;
#pragma unroll
    for (int k = 0; k < 8; ++k) if (base + k < n) out[base + k] = excl + v[k];
}

__global__ __launch_bounds__(1024) void scan_top(int* __restrict__ bsums, int nb)
{
    __shared__ int lds[1024];
    int x = (threadIdx.x < nb) ? bsums[threadIdx.x] : 0;
    lds[threadIdx.x] = x;
    __syncthreads();
    int t = x;
    for (int off = 1; off < 1024; off <<= 1) {
        int y = (threadIdx.x >= off) ? lds[threadIdx.x - off] : 0;
        __syncthreads();
        t += y;
        lds[threadIdx.x] = t;
        __syncthreads();
    }
    if (threadIdx.x < nb) bsums[threadIdx.x] = t - x;
}

__global__ __launch_bounds__(256) void scan_addback(int* __restrict__ out,
                                                    const int* __restrict__ bsums, int n)
{
    int i = blockIdx.x * blockDim.x + threadIdx.x;
    if (i < n) out[i] += bsums[i / SCAN_ELEMS];
}

// reverse-fill buckets using counts as countdown cursors (x4 unrolled)
__global__ __launch_bounds__(256) void place1(const int* __restrict__ seg, const int* __restrict__ other,
                                              const int* __restrict__ rs, int* __restrict__ counts,
                                              int* __restrict__ colsAll, int base, int E)
{
    int k0 = (blockIdx.x * blockDim.x + threadIdx.x) * 4;
    if (k0 + 3 < E) {
        int4 s4 = *(const int4*)&seg[k0];
        int4 o4 = *(const int4*)&other[k0];
        int sa = base + s4.x, sb = base + s4.y, sc = base + s4.z, sd = base + s4.w;
        int oa = atomicSub(&counts[sa], 1) - 1;
        int ob = atomicSub(&counts[sb], 1) - 1;
        int oc = atomicSub(&counts[sc], 1) - 1;
        int od = atomicSub(&counts[sd], 1) - 1;
        colsAll[rs[sa] + oa] = o4.x;
        colsAll[rs[sb] + ob] = o4.y;
        colsAll[rs[sc] + oc] = o4.z;
        colsAll[rs[sd] + od] = o4.w;
    } else {
        for (int k = k0; k < E; ++k) {
            int s = base + seg[k];
            int off = atomicSub(&counts[s], 1) - 1;
            colsAll[rs[s] + off] = other[k];
        }
    }
}

__global__ __launch_bounds__(256) void place2(const int* __restrict__ a, const int* __restrict__ b,
                                              const int* __restrict__ rs, int* __restrict__ counts,
                                              int* __restrict__ colsAll, int baseA, int baseB, int E)
{
    int k0 = (blockIdx.x * blockDim.x + threadIdx.x) * 4;
    if (k0 + 3 < E) {
        int4 a4 = *(const int4*)&a[k0];
        int4 b4 = *(const int4*)&b[k0];
        int sa0 = baseA + a4.x, sa1 = baseA + a4.y, sa2 = baseA + a4.z, sa3 = baseA + a4.w;
        int sb0 = baseB + b4.x, sb1 = baseB + b4.y, sb2 = baseB + b4.z, sb3 = baseB + b4.w;
        int oa0 = atomicSub(&counts[sa0], 1) - 1;
        int oa1 = atomicSub(&counts[sa1], 1) - 1;
        int oa2 = atomicSub(&counts[sa2], 1) - 1;
        int oa3 = atomicSub(&counts[sa3], 1) - 1;
        int ob0 = atomicSub(&counts[sb0], 1) - 1;
        int ob1 = atomicSub(&counts[sb1], 1) - 1;
        int ob2 = atomicSub(&counts[sb2], 1) - 1;
        int ob3 = atomicSub(&counts[sb3], 1) - 1;
        colsAll[rs[sa0] + oa0] = b4.x;
        colsAll[rs[sa1] + oa1] = b4.y;
        colsAll[rs[sa2] + oa2] = b4.z;
        colsAll[rs[sa3] + oa3] = b4.w;
        colsAll[rs[sb0] + ob0] = a4.x;
        colsAll[rs[sb1] + ob1] = a4.y;
        colsAll[rs[sb2] + ob2] = a4.z;
        colsAll[rs[sb3] + ob3] = a4.w;
    } else {
        for (int k = k0; k < E; ++k) {
            int av = a[k], bv = b[k];
            int sa = baseA + av;
            int offa = atomicSub(&counts[sa], 1) - 1;
            colsAll[rs[sa] + offa] = bv;
            int sb = baseB + bv;
            int offb = atomicSub(&counts[sb], 1) - 1;
            colsAll[rs[sb] + offb] = av;
        }
    }
}

// ---------------- segment aggregation (16 lanes = quarter-wave per row) ----------------
// STORE=true: out[row] = result (0 for empty rows) — replaces buffer memset.
// STORE=false: out[row] += result.
template<bool STORE>
__global__ __launch_bounds__(256) void seg_agg(
    const int* __restrict__ rs, const int* __restrict__ cols,
    const float* __restrict__ uni, const float* __restrict__ gat,
    const float* __restrict__ feat, float* __restrict__ out, int n)
{
    const int sub = threadIdx.x & 15;                       // float4 index within row
    int row = (int)((blockIdx.x * blockDim.x + threadIdx.x) >> 4);
    if (row >= n) return;
    float4* __restrict__ out4 = (float4*)out;
    int e0 = rs[row], e1 = rs[row + 1];
    if (e0 >= e1) {                    // empty row: zeros (avoid 0/0)
        if (STORE) out4[(size_t)row * 16 + sub] = make_float4(0.f, 0.f, 0.f, 0.f);
        return;
    }
    const float pu = uni[row];
    const float4* __restrict__ feat4 = (const float4*)feat;
    float4 acc = make_float4(0.f, 0.f, 0.f, 0.f);
    float ssum = 0.f;
    int e = e0;
    for (; e + 1 < e1; e += 2) {
        int c0 = cols[e], c1 = cols[e + 1];
        float g0 = gat[c0], g1 = gat[c1];
        float4 f0 = feat4[(size_t)c0 * 16 + sub];
        float4 f1 = feat4[(size_t)c1 * 16 + sub];
        float t0 = pu + g0; t0 = (t0 > 0.f) ? t0 : LRELU_SLOPE * t0;
        float t1 = pu + g1; t1 = (t1 > 0.f) ? t1 : LRELU_SLOPE * t1;
        float w0 = __expf(t0);
        float w1 = __expf(t1);
        ssum += w0 + w1;
        acc.x = fmaf(w0, f0.x, acc.x); acc.y = fmaf(w0, f0.y, acc.y);
        acc.z = fmaf(w0, f0.z, acc.z); acc.w = fmaf(w0, f0.w, acc.w);
        acc.x = fmaf(w1, f1.x, acc.x); acc.y = fmaf(w1, f1.y, acc.y);
        acc.z = fmaf(w1, f1.z, acc.z); acc.w = fmaf(w1, f1.w, acc.w);
    }
    if (e < e1) {
        int c0 = cols[e];
        float g0 = gat[c0];
        float4 f0 = feat4[(size_t)c0 * 16 + sub];
        float t0 = pu + g0; t0 = (t0 > 0.f) ? t0 : LRELU_SLOPE * t0;
        float w0 = __expf(t0);
        ssum += w0;
        acc.x = fmaf(w0, f0.x, acc.x); acc.y = fmaf(w0, f0.y, acc.y);
        acc.z = fmaf(w0, f0.z, acc.z); acc.w = fmaf(w0, f0.w, acc.w);
    }
    float inv = __frcp_rn(ssum);
    if (STORE) {
        out4[(size_t)row * 16 + sub] =
            make_float4(acc.x * inv, acc.y * inv, acc.z * inv, acc.w * inv);
    } else {
        float4 o = out4[(size_t)row * 16 + sub];
        o.x = fmaf(acc.x, inv, o.x); o.y = fmaf(acc.y, inv, o.y);
        o.z = fmaf(acc.z, inv, o.z); o.w = fmaf(acc.w, inv, o.w);
        out4[(size_t)row * 16 + sub] = o;
    }
}

extern "C" void kernel_launch(void* const* d_in, const int* in_sizes, int n_in,
                              void* d_out, int out_size, void* d_ws, size_t ws_size,
                              hipStream_t stream)
{
    const float* x0 = (const float*)d_in[0];
    const float* x1 = (const float*)d_in[1];
    const float* x2 = (const float*)d_in[2];
    const float* x3 = (const float*)d_in[3];
    const float* hbsW = (const float*)d_in[4];
    const float* hbsA = (const float*)d_in[5];
    const float* hWs  = (const float*)d_in[6];
    const float* hWt  = (const float*)d_in[7];
    const float* hA   = (const float*)d_in[8];
    const int* a0r = (const int*)d_in[9];  const int* a0c = (const int*)d_in[10];
    const int* a1r = (const int*)d_in[11]; const int* a1c = (const int*)d_in[12];
    const int* a2r = (const int*)d_in[13]; const int* a2c = (const int*)d_in[14];
    const int* c3r = (const int*)d_in[15]; const int* c3c = (const int*)d_in[16];
    const int* i1r = (const int*)d_in[17]; const int* i1c = (const int*)d_in[18];
    const int* i2r = (const int*)d_in[19]; const int* i2c = (const int*)d_in[20];
    const int* i3r = (const int*)d_in[21]; const int* i3c = (const int*)d_in[22];

    const int n0 = in_sizes[0] / 64, n1 = in_sizes[1] / 64;
    const int n2 = in_sizes[2] / 64, n3 = in_sizes[3] / 64;
    const int Ea0 = in_sizes[9],  Ea1 = in_sizes[11], Ea2 = in_sizes[13], Ec3 = in_sizes[15];
    const int Ei1 = in_sizes[17], Ei2 = in_sizes[19], Ei3 = in_sizes[21];

    int nm = n0; if (n1 > nm) nm = n1; if (n2 > nm) nm = n2; if (n3 > nm) nm = n3;

    // CSR bases (concatenated rows): adj0,adj1,adj2,c3, i1t(n0), i1s(n1), i2t(n1), i2s(n2), i3t(n2), i3s(n3)
    int b_adj0 = 0;
    int b_adj1 = b_adj0 + n0;
    int b_adj2 = b_adj1 + n1;
    int b_c3   = b_adj2 + n2;
    int b_i1t  = b_c3   + n3;
    int b_i1s  = b_i1t  + n0;
    int b_i2t  = b_i1s  + n1;
    int b_i2s  = b_i2t  + n1;
    int b_i3t  = b_i2s  + n2;
    int b_i3s  = b_i3t  + n2;
    int NC     = b_i3s  + n3 + 1;   // +1 sentinel
    long long eTot = (long long)Ea0 + Ea1 + Ea2 + Ec3 + 2LL * (Ei1 + Ei2 + Ei3);

    float* w = (float*)d_ws;
    size_t off = 0;
    auto allocf = [&](size_t nel) { float* r = w + off; off += nel; return r; };
    float* featA = allocf((size_t)nm * 64);
    float* featB = allocf((size_t)nm * 64);
    float* xl10  = allocf((size_t)n0 * 64);   // layer-1 activations
    float* xl11  = allocf((size_t)n1 * 64);
    float* xl12  = allocf((size_t)n2 * 64);
    float* xl13  = allocf((size_t)n3 * 64);
    float* pA = allocf(nm); float* qA = allocf(nm);
    float* pB = allocf(nm); float* qB = allocf(nm);
    int* counts  = (int*)allocf((size_t)NC);
    int* rs      = (int*)allocf((size_t)NC);
    int* bsums   = (int*)allocf(1024);
    int* colsAll = (int*)allocf((size_t)eTot);

    if (off * sizeof(float) > ws_size) {
        hipMemsetAsync(d_out, 0, (size_t)out_size * sizeof(float), stream);
        return;
    }

    float* out  = (float*)d_out;
    float* out0 = out;
    float* out1 = out0 + (size_t)n0 * 64;
    float* out2 = out1 + (size_t)n1 * 64;
    float* out3 = out2 + (size_t)n2 * 64;

    // Only counts needs zeroing: xl1* and out* are fully written by STORE-mode aggs.
    hipMemsetAsync(counts, 0, (size_t)NC * sizeof(int), stream);

    auto blks = [](int n, int per) { return dim3((unsigned)((n + per - 1) / per)); };

    // ---- CSR build ----
    hist1<<<blks(Ea0, 1024), 256, 0, stream>>>(a0r, counts, b_adj0, Ea0);
    hist1<<<blks(Ea1, 1024), 256, 0, stream>>>(a1r, counts, b_adj1, Ea1);
    hist1<<<blks(Ea2, 1024), 256, 0, stream>>>(a2r, counts, b_adj2, Ea2);
    hist1<<<blks(Ec3, 1024), 256, 0, stream>>>(c3r, counts, b_c3,  Ec3);
    hist2<<<blks(Ei1, 1024), 256, 0, stream>>>(i1r, i1c, counts, b_i1t, b_i1s, Ei1);
    hist2<<<blks(Ei2, 1024), 256, 0, stream>>>(i2r, i2c, counts, b_i2t, b_i2s, Ei2);
    hist2<<<blks(Ei3, 1024), 256, 0, stream>>>(i3r, i3c, counts, b_i3t, b_i3s, Ei3);

    int nb = (NC + SCAN_ELEMS - 1) / SCAN_ELEMS;
    scan_partial<<<dim3((unsigned)nb), SCAN_BLK, 0, stream>>>(counts, rs, bsums, NC);
    scan_top<<<dim3(1), 1024, 0, stream>>>(bsums, nb);
    scan_addback<<<blks(NC, 256), 256, 0, stream>>>(rs, bsums, NC);

    place1<<<blks(Ea0, 1024), 256, 0, stream>>>(a0r, a0c, rs, counts, colsAll, b_adj0, Ea0);
    place1<<<blks(Ea1, 1024), 256, 0, stream>>>(a1r, a1c, rs, counts, colsAll, b_adj1, Ea1);
    place1<<<blks(Ea2, 1024), 256, 0, stream>>>(a2r, a2c, rs, counts, colsAll, b_adj2, Ea2);
    place1<<<blks(Ec3, 1024), 256, 0, stream>>>(c3r, c3c, rs, counts, colsAll, b_c3,  Ec3);
    place2<<<blks(Ei1, 1024), 256, 0, stream>>>(i1r, i1c, rs, counts, colsAll, b_i1t, b_i1s, Ei1);
    place2<<<blks(Ei2, 1024), 256, 0, stream>>>(i2r, i2c, rs, counts, colsAll, b_i2t, b_i2s, Ei2);
    place2<<<blks(Ei3, 1024), 256, 0, stream>>>(i3r, i3c, rs, counts, colsAll, b_i3t, b_i3s, Ei3);

    auto gemm = [&](const float* xx, const float* WW, const float* aa,
                    float* mm, float* pp, float* qq, int n) {
        gemm_pq_kernel<<<blks(n, 64), 256, 0, stream>>>(xx, WW, aa, mm, pp, qq, n);
    };
    auto aggS = [&](int base, const float* uni, const float* gat,
                    const float* feat, float* outp, int n) {
        seg_agg<true><<<blks(n, 16), 256, 0, stream>>>(rs + base, colsAll, uni, gat, feat, outp, n);
    };
    auto aggA = [&](int base, const float* uni, const float* gat,
                    const float* feat, float* outp, int n) {
        seg_agg<false><<<blks(n, 16), 256, 0, stream>>>(rs + base, colsAll, uni, gat, feat, outp, n);
    };

    // ---------------- Layer 1 ----------------
    gemm(x0, hbsW + 0 * 4096, hbsA + 0 * 128, featA, pA, qA, n0);
    aggS(b_adj0, pA, qA, featA, xl10, n0);                         // x00 (store)

    gemm(x1, hWs + 0 * 4096, hA + 0 * 128, featA, pA, qA, n1);     // sm
    gemm(x0, hWt + 0 * 4096, hA + 0 * 128, featB, pB, qB, n0);     // tm
    aggA(b_i1t, qB, pA, featA, xl10, n0);  // x10 (accum into x00)
    aggS(b_i1s, qA, pB, featB, xl11, n1);  // x01 (store)

    gemm(x2, hWs + 1 * 4096, hA + 1 * 128, featA, pA, qA, n2);
    gemm(x1, hWt + 1 * 4096, hA + 1 * 128, featB, pB, qB, n1);
    aggA(b_i2t, qB, pA, featA, xl11, n1);  // x21 (accum)
    aggS(b_i2s, qA, pB, featB, xl12, n2);  // x12 (store)

    gemm(x3, hWs + 2 * 4096, hA + 2 * 128, featA, pA, qA, n3);
    gemm(x2, hWt + 2 * 4096, hA + 2 * 128, featB, pB, qB, n2);
    aggA(b_i3t, qB, pA, featA, xl12, n2);  // x32 (accum)
    aggS(b_i3s, qA, pB, featB, xl13, n3);  // x23 (store)

    // ---------------- Layer 2 ----------------
    gemm(xl10, hbsW + 1 * 4096, hbsA + 1 * 128, featA, pA, qA, n0);
    aggS(b_adj0, pA, qA, featA, out0, n0);                         // y00 (store)

    gemm(xl11, hbsW + 2 * 4096, hbsA + 2 * 128, featA, pA, qA, n1);
    aggS(b_adj1, pA, qA, featA, out1, n1);                         // y11 (store)

    gemm(xl12, hbsW + 3 * 4096, hbsA + 3 * 128, featA, pA, qA, n2);
    aggS(b_adj2, pA, qA, featA, out2, n2);                         // y22 (store)

    gemm(xl13, hbsW + 4 * 4096, hbsA + 4 * 128, featA, pA, qA, n3);
    aggS(b_c3, pA, qA, featA, out3, n3);                           // y33 (store)

    // y01 = msg_s of hbns(xl11, xl10, inc1) [Ws3, Wt3, a3]
    gemm(xl11, hWs + 3 * 4096, hA + 3 * 128, featA, pA, qA, n1);
    gemm(xl10, hWt + 3 * 4096, hA + 3 * 128, featB, pB, qB, n0);
    aggA(b_i1s, qA, pB, featB, out1, n1);                          // (accum into y11)

    // y12 = msg_s of hbns(xl12, xl11, inc2) [Ws4, Wt4, a4]
    gemm(xl12, hWs + 4 * 4096, hA + 4 * 128, featA, pA, qA, n2);
    gemm(xl11, hWt + 4 * 4096, hA + 4 * 128, featB, pB, qB, n1);
    aggA(b_i2s, qA, pB, featB, out2, n2);                          // (accum into y22)

    // y23 = msg_s of hbns(xl13, xl12, inc3) [Ws5, Wt5, a5]
    gemm(xl13, hWs + 5 * 4096, hA + 5 * 128, featA, pA, qA, n3);
    gemm(xl12, hWt + 5 * 4096, hA + 5 * 128, featB, pB, qB, n2);
    aggA(b_i3s, qA, pB, featB, out3, n3);                          // (accum into y33)
}

// Round 5
// 1449.234 us; speedup vs baseline: 1.6885x; 1.1455x over previous
//
#include <hip/hip_runtime.h>
#include <cstddef>
#include <cstdint>

#define LRELU_SLOPE 0.2f
#define SCAN_BLK 256
#define SCAN_ELEMS 2048   // 8 per thread

#define XS_STRIDE 68      // 64 + 4 pad: keeps float4 alignment, breaks bank alignment

// explicit stream-ordered zeroing (NOT hipMemsetAsync: a graph-replay anomaly in
// round 4 left cursors unzeroed on calls >=2; a plain kernel launch is unambiguous)
__global__ __launch_bounds__(256) void zero_ints(int* __restrict__ p, int n)
{
    int i = blockIdx.x * blockDim.x + threadIdx.x;
    if (i < n) p[i] = 0;
}

// m = x @ W (64x64), p = m·a1, q = m·a2
// One block per 64-row tile. W and x-tile staged in LDS. Wave w computes rows
// [16w,16w+16) x all 64 cols; each thread a 4x4 register tile.
__global__ __launch_bounds__(256, 4) void gemm_pq_kernel(
    const float* __restrict__ x, const float* __restrict__ W,
    const float* __restrict__ a, float* __restrict__ m,
    float* __restrict__ p, float* __restrict__ q, int n)
{
    __shared__ float xs[64 * XS_STRIDE];
    __shared__ float ws[64 * XS_STRIDE];

    const int t = threadIdx.x;
    const int rbase = blockIdx.x * 64;

    // stage W: 4096 floats = 1024 float4, 4 per thread (coalesced)
    {
        const float4* __restrict__ W4 = (const float4*)W;
#pragma unroll
        for (int u = 0; u < 4; ++u) {
            int f = t + 256 * u;          // float4 index
            int k = f >> 4, g = f & 15;
            float4 v = W4[f];
            *(float4*)&ws[k * XS_STRIDE + 4 * g] = v;
        }
    }
    // stage x tile (row-guarded; OOB rows zero-filled)
    {
        const float4* __restrict__ x4 = (const float4*)x;
#pragma unroll
        for (int u = 0; u < 4; ++u) {
            int f = t + 256 * u;
            int r = f >> 4, g = f & 15;
            float4 v = make_float4(0.f, 0.f, 0.f, 0.f);
            if (rbase + r < n) v = x4[(size_t)(rbase + r) * 16 + g];
            *(float4*)&xs[r * XS_STRIDE + 4 * g] = v;
        }
    }
    __syncthreads();

    const int lane = t & 63;
    const int wv   = t >> 6;
    const int s    = lane & 15;          // col group (16 groups cover all 64 cols)
    const int rg   = lane >> 4;          // row group within wave
    const int c0   = 4 * s;
    const int r0   = 16 * wv + 4 * rg;   // tile-local row base

    float acc[4][4] = {{0.f}};

#pragma unroll 2
    for (int k0 = 0; k0 < 64; k0 += 4) {
        float xr[4][4], wr[4][4];
#pragma unroll
        for (int i = 0; i < 4; ++i) {
            float4 v = *(const float4*)&xs[(r0 + i) * XS_STRIDE + k0];
            xr[i][0] = v.x; xr[i][1] = v.y; xr[i][2] = v.z; xr[i][3] = v.w;
        }
#pragma unroll
        for (int kk = 0; kk < 4; ++kk) {
            float4 v = *(const float4*)&ws[(k0 + kk) * XS_STRIDE + c0];
            wr[kk][0] = v.x; wr[kk][1] = v.y; wr[kk][2] = v.z; wr[kk][3] = v.w;
        }
#pragma unroll
        for (int kk = 0; kk < 4; ++kk)
#pragma unroll
            for (int i = 0; i < 4; ++i)
#pragma unroll
                for (int j = 0; j < 4; ++j)
                    acc[i][j] = fmaf(xr[i][kk], wr[kk][j], acc[i][j]);
    }

    // store m (4 rows x float4, 256B-contiguous per 16-lane group)
#pragma unroll
    for (int i = 0; i < 4; ++i) {
        int r = rbase + r0 + i;
        if (r < n)
            *(float4*)&m[(size_t)r * 64 + c0] =
                make_float4(acc[i][0], acc[i][1], acc[i][2], acc[i][3]);
    }

    // p,q: per-thread partial dot over own 4 cols, then butterfly over 16 col-groups
    const float4 a1v = *(const float4*)&a[c0];
    const float4 a2v = *(const float4*)&a[64 + c0];
    float pp[4], qq[4];
#pragma unroll
    for (int i = 0; i < 4; ++i) {
        pp[i] = fmaf(acc[i][3], a1v.w, fmaf(acc[i][2], a1v.z,
                fmaf(acc[i][1], a1v.y, acc[i][0] * a1v.x)));
        qq[i] = fmaf(acc[i][3], a2v.w, fmaf(acc[i][2], a2v.z,
                fmaf(acc[i][1], a2v.y, acc[i][0] * a2v.x)));
    }
#pragma unroll
    for (int off = 1; off < 16; off <<= 1) {
#pragma unroll
        for (int i = 0; i < 4; ++i) {
            pp[i] += __shfl_xor(pp[i], off);
            qq[i] += __shfl_xor(qq[i], off);
        }
    }
    if (s == 0) {
#pragma unroll
        for (int i = 0; i < 4; ++i) {
            int r = rbase + r0 + i;
            if (r < n) { p[r] = pp[i]; q[r] = qq[i]; }
        }
    }
}

// =========================================================================
// PADDED-BUCKET CSR (primary path): one fused scatter pass, no hist/scan.
// bucket[row*CAP + atomicAdd(&cursor[row],1)] = other
// Cursors are zeroed by zero_ints BEFORE scatter and AFTER the last agg
// (self-restoring across calls, like the old place-path's atomicSub drain).
// =========================================================================
struct SJob {
    const int* u; const int* v;     // edge endpoint arrays
    int* colsU;                     // padded bucket arena for u-side rows
    int* colsV;                     // v-side arena (type-2 jobs), else null
    int E; int blk0;                // edges, first block of this job
    int baseU; int capU;            // cursor base, bucket capacity
    int baseV; int capV;            // -1 if type-1 (no v-side scatter)
};
struct SJobs { SJob j[7]; int totalBlocks; };

#define SC_PER_TH 2
__global__ __launch_bounds__(256) void scatter_direct(SJobs P, int* __restrict__ cursor)
{
    int b = blockIdx.x;
    int ji = 0;
#pragma unroll
    for (int t = 1; t < 7; ++t) if (b >= P.j[t].blk0) ji = t;
    const SJob J = P.j[ji];
    int k = (b - J.blk0) * (256 * SC_PER_TH) + threadIdx.x;
#pragma unroll
    for (int r = 0; r < SC_PER_TH; ++r, k += 256) {
        if (k < J.E) {
            int uv = J.u[k], vv = J.v[k];
            int off = atomicAdd(&cursor[J.baseU + uv], 1);
            if (off < J.capU) J.colsU[(size_t)uv * J.capU + off] = vv;
            if (J.baseV >= 0) {
                int off2 = atomicAdd(&cursor[J.baseV + vv], 1);
                if (off2 < J.capV) J.colsV[(size_t)vv * J.capV + off2] = uv;
            }
        }
    }
}

// padded-bucket segment aggregation
template<bool STORE>
__global__ __launch_bounds__(256) void seg_agg_pad(
    const int* __restrict__ cnt, const int* __restrict__ cols, int CAP,
    const float* __restrict__ uni, const float* __restrict__ gat,
    const float* __restrict__ feat, float* __restrict__ out, int n)
{
    const int sub = threadIdx.x & 15;
    int row = (int)((blockIdx.x * blockDim.x + threadIdx.x) >> 4);
    if (row >= n) return;
    float4* __restrict__ out4 = (float4*)out;
    int c = cnt[row]; if (c > CAP) c = CAP;
    if (c <= 0) {
        if (STORE) out4[(size_t)row * 16 + sub] = make_float4(0.f, 0.f, 0.f, 0.f);
        return;
    }
    const float pu = uni[row];
    const float4* __restrict__ feat4 = (const float4*)feat;
    float4 acc = make_float4(0.f, 0.f, 0.f, 0.f);
    float ssum = 0.f;
    size_t e = (size_t)row * CAP;
    size_t e1 = e + c;
    for (; e + 1 < e1; e += 2) {
        int c0 = cols[e], c1 = cols[e + 1];
        float g0 = gat[c0], g1 = gat[c1];
        float4 f0 = feat4[(size_t)c0 * 16 + sub];
        float4 f1 = feat4[(size_t)c1 * 16 + sub];
        float t0 = pu + g0; t0 = (t0 > 0.f) ? t0 : LRELU_SLOPE * t0;
        float t1 = pu + g1; t1 = (t1 > 0.f) ? t1 : LRELU_SLOPE * t1;
        float w0 = __expf(t0);
        float w1 = __expf(t1);
        ssum += w0 + w1;
        acc.x = fmaf(w0, f0.x, acc.x); acc.y = fmaf(w0, f0.y, acc.y);
        acc.z = fmaf(w0, f0.z, acc.z); acc.w = fmaf(w0, f0.w, acc.w);
        acc.x = fmaf(w1, f1.x, acc.x); acc.y = fmaf(w1, f1.y, acc.y);
        acc.z = fmaf(w1, f1.z, acc.z); acc.w = fmaf(w1, f1.w, acc.w);
    }
    if (e < e1) {
        int c0 = cols[e];
        float g0 = gat[c0];
        float4 f0 = feat4[(size_t)c0 * 16 + sub];
        float t0 = pu + g0; t0 = (t0 > 0.f) ? t0 : LRELU_SLOPE * t0;
        float w0 = __expf(t0);
        ssum += w0;
        acc.x = fmaf(w0, f0.x, acc.x); acc.y = fmaf(w0, f0.y, acc.y);
        acc.z = fmaf(w0, f0.z, acc.z); acc.w = fmaf(w0, f0.w, acc.w);
    }
    float inv = __frcp_rn(ssum);
    if (STORE) {
        out4[(size_t)row * 16 + sub] =
            make_float4(acc.x * inv, acc.y * inv, acc.z * inv, acc.w * inv);
    } else {
        float4 o = out4[(size_t)row * 16 + sub];
        o.x = fmaf(acc.x, inv, o.x); o.y = fmaf(acc.y, inv, o.y);
        o.z = fmaf(acc.z, inv, o.z); o.w = fmaf(acc.w, inv, o.w);
        out4[(size_t)row * 16 + sub] = o;
    }
}

// =========================================================================
// FALLBACK path: hist + scan + place CSR build (self-restoring via atomicSub)
// =========================================================================
__global__ __launch_bounds__(256) void hist1(const int* __restrict__ seg,
                                             int* __restrict__ counts, int base, int E)
{
    int k0 = (blockIdx.x * blockDim.x + threadIdx.x) * 4;
    if (k0 + 3 < E) {
        int4 s4 = *(const int4*)&seg[k0];
        atomicAdd(&counts[base + s4.x], 1);
        atomicAdd(&counts[base + s4.y], 1);
        atomicAdd(&counts[base + s4.z], 1);
        atomicAdd(&counts[base + s4.w], 1);
    } else {
        for (int k = k0; k < E; ++k) atomicAdd(&counts[base + seg[k]], 1);
    }
}

__global__ __launch_bounds__(256) void hist2(const int* __restrict__ a, const int* __restrict__ b,
                                             int* __restrict__ counts, int baseA, int baseB, int E)
{
    int k0 = (blockIdx.x * blockDim.x + threadIdx.x) * 4;
    if (k0 + 3 < E) {
        int4 a4 = *(const int4*)&a[k0];
        int4 b4 = *(const int4*)&b[k0];
        atomicAdd(&counts[baseA + a4.x], 1);
        atomicAdd(&counts[baseA + a4.y], 1);
        atomicAdd(&counts[baseA + a4.z], 1);
        atomicAdd(&counts[baseA + a4.w], 1);
        atomicAdd(&counts[baseB + b4.x], 1);
        atomicAdd(&counts[baseB + b4.y], 1);
        atomicAdd(&counts[baseB + b4.z], 1);
        atomicAdd(&counts[baseB + b4.w], 1);
    } else {
        for (int k = k0; k < E; ++k) {
            atomicAdd(&counts[baseA + a[k]], 1);
            atomicAdd(&counts[baseB + b[k]], 1);
        }
    }
}

__global__ __launch_bounds__(SCAN_BLK) void scan_partial(const int* __restrict__ in,
                                                         int* __restrict__ out,
                                                         int* __restrict__ bsums, int n)
{
    __shared__ int lds[SCAN_BLK];
    int base = blockIdx.x * SCAN_ELEMS + threadIdx.x * 8;
    int v[8]; int s = 0;
#pragma unroll
    for (int k = 0; k < 8; ++k) { int x = (base + k < n) ? in[base + k] : 0; v[k] = s; s += x; }
    lds[threadIdx.x] = s;
    __syncthreads();
    int t = s;
    for (int off = 1; off < SCAN_BLK; off <<= 1) {
        int y = (threadIdx.x >= off) ? lds[threadIdx.x - off] : 0;
        __syncthreads();
        t += y;
        lds[threadIdx.x] = t;
        __syncthreads();
    }
    int excl = t - s;
    if (threadIdx.x == SCAN_BLK - 1) bsums[blockIdx.x] = t;
#pragma unroll
    for (int k = 0; k < 8; ++k) if (base + k < n) out[base + k] = excl + v[k];
}

__global__ __launch_bounds__(1024) void scan_top(int* __restrict__ bsums, int nb)
{
    __shared__ int lds[1024];
    int x = (threadIdx.x < nb) ? bsums[threadIdx.x] : 0;
    lds[threadIdx.x] = x;
    __syncthreads();
    int t = x;
    for (int off = 1; off < 1024; off <<= 1) {
        int y = (threadIdx.x >= off) ? lds[threadIdx.x - off] : 0;
        __syncthreads();
        t += y;
        lds[threadIdx.x] = t;
        __syncthreads();
    }
    if (threadIdx.x < nb) bsums[threadIdx.x] = t - x;
}

__global__ __launch_bounds__(256) void scan_addback(int* __restrict__ out,
                                                    const int* __restrict__ bsums, int n)
{
    int i = blockIdx.x * blockDim.x + threadIdx.x;
    if (i < n) out[i] += bsums[i / SCAN_ELEMS];
}

__global__ __launch_bounds__(256) void place1(const int* __restrict__ seg, const int* __restrict__ other,
                                              const int* __restrict__ rs, int* __restrict__ counts,
                                              int* __restrict__ colsAll, int base, int E)
{
    int k = blockIdx.x * blockDim.x + threadIdx.x;
    if (k >= E) return;
    int s = base + seg[k];
    int off = atomicSub(&counts[s], 1) - 1;
    colsAll[rs[s] + off] = other[k];
}

__global__ __launch_bounds__(256) void place2(const int* __restrict__ a, const int* __restrict__ b,
                                              const int* __restrict__ rs, int* __restrict__ counts,
                                              int* __restrict__ colsAll, int baseA, int baseB, int E)
{
    int k = blockIdx.x * blockDim.x + threadIdx.x;
    if (k >= E) return;
    int av = a[k], bv = b[k];
    int sa = baseA + av;
    int offa = atomicSub(&counts[sa], 1) - 1;
    colsAll[rs[sa] + offa] = bv;
    int sb = baseB + bv;
    int offb = atomicSub(&counts[sb], 1) - 1;
    colsAll[rs[sb] + offb] = av;
}

template<bool STORE>
__global__ __launch_bounds__(256) void seg_agg(
    const int* __restrict__ rs, const int* __restrict__ cols,
    const float* __restrict__ uni, const float* __restrict__ gat,
    const float* __restrict__ feat, float* __restrict__ out, int n)
{
    const int sub = threadIdx.x & 15;
    int row = (int)((blockIdx.x * blockDim.x + threadIdx.x) >> 4);
    if (row >= n) return;
    float4* __restrict__ out4 = (float4*)out;
    int e0 = rs[row], e1 = rs[row + 1];
    if (e0 >= e1) {
        if (STORE) out4[(size_t)row * 16 + sub] = make_float4(0.f, 0.f, 0.f, 0.f);
        return;
    }
    const float pu = uni[row];
    const float4* __restrict__ feat4 = (const float4*)feat;
    float4 acc = make_float4(0.f, 0.f, 0.f, 0.f);
    float ssum = 0.f;
    int e = e0;
    for (; e + 1 < e1; e += 2) {
        int c0 = cols[e], c1 = cols[e + 1];
        float g0 = gat[c0], g1 = gat[c1];
        float4 f0 = feat4[(size_t)c0 * 16 + sub];
        float4 f1 = feat4[(size_t)c1 * 16 + sub];
        float t0 = pu + g0; t0 = (t0 > 0.f) ? t0 : LRELU_SLOPE * t0;
        float t1 = pu + g1; t1 = (t1 > 0.f) ? t1 : LRELU_SLOPE * t1;
        float w0 = __expf(t0);
        float w1 = __expf(t1);
        ssum += w0 + w1;
        acc.x = fmaf(w0, f0.x, acc.x); acc.y = fmaf(w0, f0.y, acc.y);
        acc.z = fmaf(w0, f0.z, acc.z); acc.w = fmaf(w0, f0.w, acc.w);
        acc.x = fmaf(w1, f1.x, acc.x); acc.y = fmaf(w1, f1.y, acc.y);
        acc.z = fmaf(w1, f1.z, acc.z); acc.w = fmaf(w1, f1.w, acc.w);
    }
    if (e < e1) {
        int c0 = cols[e];
        float g0 = gat[c0];
        float4 f0 = feat4[(size_t)c0 * 16 + sub];
        float t0 = pu + g0; t0 = (t0 > 0.f) ? t0 : LRELU_SLOPE * t0;
        float w0 = __expf(t0);
        ssum += w0;
        acc.x = fmaf(w0, f0.x, acc.x); acc.y = fmaf(w0, f0.y, acc.y);
        acc.z = fmaf(w0, f0.z, acc.z); acc.w = fmaf(w0, f0.w, acc.w);
    }
    float inv = __frcp_rn(ssum);
    if (STORE) {
        out4[(size_t)row * 16 + sub] =
            make_float4(acc.x * inv, acc.y * inv, acc.z * inv, acc.w * inv);
    } else {
        float4 o = out4[(size_t)row * 16 + sub];
        o.x = fmaf(acc.x, inv, o.x); o.y = fmaf(acc.y, inv, o.y);
        o.z = fmaf(acc.z, inv, o.z); o.w = fmaf(acc.w, inv, o.w);
        out4[(size_t)row * 16 + sub] = o;
    }
}

extern "C" void kernel_launch(void* const* d_in, const int* in_sizes, int n_in,
                              void* d_out, int out_size, void* d_ws, size_t ws_size,
                              hipStream_t stream)
{
    const float* x0 = (const float*)d_in[0];
    const float* x1 = (const float*)d_in[1];
    const float* x2 = (const float*)d_in[2];
    const float* x3 = (const float*)d_in[3];
    const float* hbsW = (const float*)d_in[4];
    const float* hbsA = (const float*)d_in[5];
    const float* hWs  = (const float*)d_in[6];
    const float* hWt  = (const float*)d_in[7];
    const float* hA   = (const float*)d_in[8];
    const int* a0r = (const int*)d_in[9];  const int* a0c = (const int*)d_in[10];
    const int* a1r = (const int*)d_in[11]; const int* a1c = (const int*)d_in[12];
    const int* a2r = (const int*)d_in[13]; const int* a2c = (const int*)d_in[14];
    const int* c3r = (const int*)d_in[15]; const int* c3c = (const int*)d_in[16];
    const int* i1r = (const int*)d_in[17]; const int* i1c = (const int*)d_in[18];
    const int* i2r = (const int*)d_in[19]; const int* i2c = (const int*)d_in[20];
    const int* i3r = (const int*)d_in[21]; const int* i3c = (const int*)d_in[22];

    const int n0 = in_sizes[0] / 64, n1 = in_sizes[1] / 64;
    const int n2 = in_sizes[2] / 64, n3 = in_sizes[3] / 64;
    const int Ea0 = in_sizes[9],  Ea1 = in_sizes[11], Ea2 = in_sizes[13], Ec3 = in_sizes[15];
    const int Ei1 = in_sizes[17], Ei2 = in_sizes[19], Ei3 = in_sizes[21];

    int nm = n0; if (n1 > nm) nm = n1; if (n2 > nm) nm = n2; if (n3 > nm) nm = n3;

    // Row-space bases (10 structures, concatenated)
    int b_adj0 = 0;
    int b_adj1 = b_adj0 + n0;
    int b_adj2 = b_adj1 + n1;
    int b_c3   = b_adj2 + n2;
    int b_i1t  = b_c3   + n3;
    int b_i1s  = b_i1t  + n0;
    int b_i2t  = b_i1s  + n1;
    int b_i2s  = b_i2t  + n1;
    int b_i3t  = b_i2s  + n2;
    int b_i3s  = b_i3t  + n2;
    int NC     = b_i3s  + n3 + 1;   // +1 sentinel (fallback scan)
    long long eTot = (long long)Ea0 + Ea1 + Ea2 + Ec3 + 2LL * (Ei1 + Ei2 + Ei3);

    float* w = (float*)d_ws;
    size_t off = 0;
    auto allocf = [&](size_t nel) { float* r = w + off; off += nel; return r; };
    float* featA = allocf((size_t)nm * 64);
    float* featB = allocf((size_t)nm * 64);
    float* xl10  = allocf((size_t)n0 * 64);
    float* xl11  = allocf((size_t)n1 * 64);
    float* xl12  = allocf((size_t)n2 * 64);
    float* xl13  = allocf((size_t)n3 * 64);
    float* pA = allocf(nm); float* qA = allocf(nm);
    float* pB = allocf(nm); float* qB = allocf(nm);
    int* counts  = (int*)allocf((size_t)NC);    // cursor (padded) / counts (fallback)
    int* rs      = (int*)allocf((size_t)NC);
    int* bsums   = (int*)allocf(1024);

    // Padded-bucket arena sizing: 10 structures {E, rows, base}
    const int stE[10]    = {Ea0, Ea1, Ea2, Ec3, Ei1, Ei1, Ei2, Ei2, Ei3, Ei3};
    const int stRows[10] = {n0,  n1,  n2,  n3,  n0,  n1,  n1,  n2,  n2,  n3};
    const int stBase[10] = {b_adj0, b_adj1, b_adj2, b_c3, b_i1t, b_i1s, b_i2t, b_i2s, b_i3t, b_i3s};
    int caps[10];
    long long arOff[10];
    long long arElems = 0;
    for (int i = 0; i < 10; ++i) {
        long long lam2 = (5LL * stE[i]) / (2LL * stRows[i]);  // 2.5*lambda
        int cap = (int)((lam2 + 16 + 7) & ~7LL);
        caps[i] = cap;
        arOff[i] = arElems;
        arElems += (long long)stRows[i] * cap;
    }
    bool usePad = (off + (size_t)arElems + 64) * sizeof(float) <= ws_size;

    int* arena   = nullptr;
    int* colsAll = nullptr;
    if (usePad) arena = (int*)allocf((size_t)arElems);
    else        colsAll = (int*)allocf((size_t)eTot);

    if (off * sizeof(float) > ws_size) {
        hipMemsetAsync(d_out, 0, (size_t)out_size * sizeof(float), stream);
        return;
    }

    float* out  = (float*)d_out;
    float* out0 = out;
    float* out1 = out0 + (size_t)n0 * 64;
    float* out2 = out1 + (size_t)n1 * 64;
    float* out3 = out2 + (size_t)n2 * 64;

    auto blks = [](int n, int per) { return dim3((unsigned)((n + per - 1) / per)); };

    // explicit stream-ordered zeroing of cursors/counts (see zero_ints comment)
    zero_ints<<<blks(NC, 256), 256, 0, stream>>>(counts, NC);

    // ---- CSR build ----
    if (usePad) {
        // single fused scatter pass: 1 atomic + 1 store per edge-visit
        SJobs P;
        int blk = 0;
        auto mkjob = [&](int ji, const int* u, const int* v, int E,
                         int iu, int iv /* -1 for type-1 */) {
            SJob& J = P.j[ji];
            J.u = u; J.v = v; J.E = E; J.blk0 = blk;
            J.baseU = stBase[iu]; J.capU = caps[iu]; J.colsU = arena + arOff[iu];
            if (iv >= 0) { J.baseV = stBase[iv]; J.capV = caps[iv]; J.colsV = arena + arOff[iv]; }
            else         { J.baseV = -1; J.capV = 0; J.colsV = nullptr; }
            blk += (E + 256 * SC_PER_TH - 1) / (256 * SC_PER_TH);
        };
        mkjob(0, a0r, a0c, Ea0, 0, -1);
        mkjob(1, a1r, a1c, Ea1, 1, -1);
        mkjob(2, a2r, a2c, Ea2, 2, -1);
        mkjob(3, c3r, c3c, Ec3, 3, -1);
        mkjob(4, i1r, i1c, Ei1, 4, 5);
        mkjob(5, i2r, i2c, Ei2, 6, 7);
        mkjob(6, i3r, i3c, Ei3, 8, 9);
        P.totalBlocks = blk;
        scatter_direct<<<dim3((unsigned)blk), 256, 0, stream>>>(P, counts);
    } else {
        hist1<<<blks(Ea0, 1024), 256, 0, stream>>>(a0r, counts, b_adj0, Ea0);
        hist1<<<blks(Ea1, 1024), 256, 0, stream>>>(a1r, counts, b_adj1, Ea1);
        hist1<<<blks(Ea2, 1024), 256, 0, stream>>>(a2r, counts, b_adj2, Ea2);
        hist1<<<blks(Ec3, 1024), 256, 0, stream>>>(c3r, counts, b_c3,  Ec3);
        hist2<<<blks(Ei1, 1024), 256, 0, stream>>>(i1r, i1c, counts, b_i1t, b_i1s, Ei1);
        hist2<<<blks(Ei2, 1024), 256, 0, stream>>>(i2r, i2c, counts, b_i2t, b_i2s, Ei2);
        hist2<<<blks(Ei3, 1024), 256, 0, stream>>>(i3r, i3c, counts, b_i3t, b_i3s, Ei3);

        int nb = (NC + SCAN_ELEMS - 1) / SCAN_ELEMS;
        scan_partial<<<dim3((unsigned)nb), SCAN_BLK, 0, stream>>>(counts, rs, bsums, NC);
        scan_top<<<dim3(1), 1024, 0, stream>>>(bsums, nb);
        scan_addback<<<blks(NC, 256), 256, 0, stream>>>(rs, bsums, NC);

        place1<<<blks(Ea0, 256), 256, 0, stream>>>(a0r, a0c, rs, counts, colsAll, b_adj0, Ea0);
        place1<<<blks(Ea1, 256), 256, 0, stream>>>(a1r, a1c, rs, counts, colsAll, b_adj1, Ea1);
        place1<<<blks(Ea2, 256), 256, 0, stream>>>(a2r, a2c, rs, counts, colsAll, b_adj2, Ea2);
        place1<<<blks(Ec3, 256), 256, 0, stream>>>(c3r, c3c, rs, counts, colsAll, b_c3,  Ec3);
        place2<<<blks(Ei1, 256), 256, 0, stream>>>(i1r, i1c, rs, counts, colsAll, b_i1t, b_i1s, Ei1);
        place2<<<blks(Ei2, 256), 256, 0, stream>>>(i2r, i2c, rs, counts, colsAll, b_i2t, b_i2s, Ei2);
        place2<<<blks(Ei3, 256), 256, 0, stream>>>(i3r, i3c, rs, counts, colsAll, b_i3t, b_i3s, Ei3);
    }

    auto gemm = [&](const float* xx, const float* WW, const float* aa,
                    float* mm, float* pp, float* qq, int n) {
        gemm_pq_kernel<<<blks(n, 64), 256, 0, stream>>>(xx, WW, aa, mm, pp, qq, n);
    };
    // structure index -> agg over that padded/CSR structure
    auto aggS = [&](int si, const float* uni, const float* gat,
                    const float* feat, float* outp, int n) {
        if (usePad)
            seg_agg_pad<true><<<blks(n, 16), 256, 0, stream>>>(
                counts + stBase[si], arena + arOff[si], caps[si], uni, gat, feat, outp, n);
        else
            seg_agg<true><<<blks(n, 16), 256, 0, stream>>>(
                rs + stBase[si], colsAll, uni, gat, feat, outp, n);
    };
    auto aggA = [&](int si, const float* uni, const float* gat,
                    const float* feat, float* outp, int n) {
        if (usePad)
            seg_agg_pad<false><<<blks(n, 16), 256, 0, stream>>>(
                counts + stBase[si], arena + arOff[si], caps[si], uni, gat, feat, outp, n);
        else
            seg_agg<false><<<blks(n, 16), 256, 0, stream>>>(
                rs + stBase[si], colsAll, uni, gat, feat, outp, n);
    };
    // structure indices: 0=adj0 1=adj1 2=adj2 3=c3 4=i1t 5=i1s 6=i2t 7=i2s 8=i3t 9=i3s

    // ---------------- Layer 1 ----------------
    gemm(x0, hbsW + 0 * 4096, hbsA + 0 * 128, featA, pA, qA, n0);
    aggS(0, pA, qA, featA, xl10, n0);                              // x00 (store)

    gemm(x1, hWs + 0 * 4096, hA + 0 * 128, featA, pA, qA, n1);     // sm
    gemm(x0, hWt + 0 * 4096, hA + 0 * 128, featB, pB, qB, n0);     // tm
    aggA(4, qB, pA, featA, xl10, n0);      // x10 (accum into x00)
    aggS(5, qA, pB, featB, xl11, n1);      // x01 (store)

    gemm(x2, hWs + 1 * 4096, hA + 1 * 128, featA, pA, qA, n2);
    gemm(x1, hWt + 1 * 4096, hA + 1 * 128, featB, pB, qB, n1);
    aggA(6, qB, pA, featA, xl11, n1);      // x21 (accum)
    aggS(7, qA, pB, featB, xl12, n2);      // x12 (store)

    gemm(x3, hWs + 2 * 4096, hA + 2 * 128, featA, pA, qA, n3);
    gemm(x2, hWt + 2 * 4096, hA + 2 * 128, featB, pB, qB, n2);
    aggA(8, qB, pA, featA, xl12, n2);      // x32 (accum)
    aggS(9, qA, pB, featB, xl13, n3);      // x23 (store)

    // ---------------- Layer 2 ----------------
    gemm(xl10, hbsW + 1 * 4096, hbsA + 1 * 128, featA, pA, qA, n0);
    aggS(0, pA, qA, featA, out0, n0);                              // y00 (store)

    gemm(xl11, hbsW + 2 * 4096, hbsA + 2 * 128, featA, pA, qA, n1);
    aggS(1, pA, qA, featA, out1, n1);                              // y11 (store)

    gemm(xl12, hbsW + 3 * 4096, hbsA + 3 * 128, featA, pA, qA, n2);
    aggS(2, pA, qA, featA, out2, n2);                              // y22 (store)

    gemm(xl13, hbsW + 4 * 4096, hbsA + 4 * 128, featA, pA, qA, n3);
    aggS(3, pA, qA, featA, out3, n3);                              // y33 (store)

    // y01 = msg_s of hbns(xl11, xl10, inc1) [Ws3, Wt3, a3]
    gemm(xl11, hWs + 3 * 4096, hA + 3 * 128, featA, pA, qA, n1);
    gemm(xl10, hWt + 3 * 4096, hA + 3 * 128, featB, pB, qB, n0);
    aggA(5, qA, pB, featB, out1, n1);                              // accum into y11

    // y12 = msg_s of hbns(xl12, xl11, inc2) [Ws4, Wt4, a4]
    gemm(xl12, hWs + 4 * 4096, hA + 4 * 128, featA, pA, qA, n2);
    gemm(xl11, hWt + 4 * 4096, hA + 4 * 128, featB, pB, qB, n1);
    aggA(7, qA, pB, featB, out2, n2);                              // accum into y22

    // y23 = msg_s of hbns(xl13, xl12, inc3) [Ws5, Wt5, a5]
    gemm(xl13, hWs + 5 * 4096, hA + 5 * 128, featA, pA, qA, n3);
    gemm(xl12, hWt + 5 * 4096, hA + 5 * 128, featB, pB, qB, n2);
    aggA(9, qA, pB, featB, out3, n3);                              // accum into y33

    // self-restore: cursors re-enter the next call at 0 even if the leading
    // zeroing were ever elided by replay machinery (pad path leaves counts hot)
    if (usePad) zero_ints<<<blks(NC, 256), 256, 0, stream>>>(counts, NC);
}